// Round 12
// baseline (1158.217 us; speedup 1.0000x reference)
//
#include <hip/hip_runtime.h>
#include <hip/hip_bf16.h>
#include <cstddef>
#include <cstdint>

#define NNODE  20000
#define MPAD   20096        // 314*64
#define NEDGE  240000
#define NGRAPH 200
#define DIN    118
#define HD     256
#define NBASIS 10
#define RHID   100
#define NLAYER 3
#define NSH    9
#define SHSTR  16           // sh row stride in f16 (32 B); [8]=Y8, [10..11]=src bits
#define KTP    (NSH * HD)   // 2304
#define KTOT   (KTP + HD)   // 2560
#define KR2    128          // padded radial K
#define KEMB   128          // padded embed K (118 -> 128)
#define SPLITK 4
#define KCH    (KTOT / SPLITK)   // 640
#define NRT    (MPAD / 64)       // 314 row tiles

typedef _Float16 f16;
typedef _Float16 f16x2 __attribute__((ext_vector_type(2)));
typedef _Float16 f16x4 __attribute__((ext_vector_type(4)));
typedef _Float16 f16x8 __attribute__((ext_vector_type(8)));
typedef float    f32x4 __attribute__((ext_vector_type(4)));

__device__ __forceinline__ float gelu_tanh(float v) {
  float v3 = v * v * v;
  return 0.5f * v * (1.f + tanhf(0.7978845608028654f * (v + 0.044715f * v3)));
}

// within 64-group: physical row rho holds true column perm(rho)
__device__ __forceinline__ int perm64(int rho) {
  return (rho & ~63) | ((rho & 15) * 4 + ((rho >> 4) & 3));
}
__device__ __forceinline__ int inv_perm64(int n) {
  return (n & ~63) | (((n & 3) << 4) | ((n >> 2) & 15));
}

// ---------------- CSR build ----------------
__global__ void deg_hist_kernel(const int* __restrict__ ei, int* __restrict__ deg)
{
  int e = blockIdx.x * 256 + threadIdx.x;
  if (e >= NEDGE) return;
  atomicAdd(&deg[ei[NEDGE + e]], 1);
}

__global__ void scan_kernel(const int* __restrict__ deg, int* __restrict__ rowptr)
{
  __shared__ int part[256];
  int t = threadIdx.x;
  const int chunk = (NNODE + 255) / 256;
  int start = t * chunk;
  int end = min(start + chunk, NNODE);
  int s = 0;
  for (int i = start; i < end; ++i) s += deg[i];
  part[t] = s;
  __syncthreads();
  for (int off = 1; off < 256; off <<= 1) {
    int v = (t >= off) ? part[t - off] : 0;
    __syncthreads();
    part[t] += v;
    __syncthreads();
  }
  int run = (t == 0) ? 0 : part[t - 1];
  for (int i = start; i < end; ++i) { rowptr[i] = run; run += deg[i]; }
  if (t == 255) rowptr[NNODE] = run;
}

// -------- edge geometry + scatter into CSR (dst-sorted) position --------
__global__ void edge_geom_kernel(const float* __restrict__ pos,
                                 const float* __restrict__ shift,
                                 const float* __restrict__ lat,
                                 const int* __restrict__ ei,
                                 const int* __restrict__ batch,
                                 const int* __restrict__ rowptr,
                                 int* __restrict__ cursor,
                                 f16* __restrict__ sh_s,
                                 float* __restrict__ lens_s)
{
  int e = blockIdx.x * 256 + threadIdx.x;
  if (e >= NEDGE) return;
  int src = ei[e];
  int dst = ei[NEDGE + e];
  int b = batch[src];
  const float* L = lat + (size_t)b * 9;
  float s0 = shift[e * 3 + 0], s1 = shift[e * 3 + 1], s2 = shift[e * 3 + 2];
  float ev[3];
#pragma unroll
  for (int j = 0; j < 3; ++j)
    ev[j] = pos[dst * 3 + j] - pos[src * 3 + j] + s0 * L[j] + s1 * L[3 + j] + s2 * L[6 + j];
  float len = sqrtf(ev[0] * ev[0] + ev[1] * ev[1] + ev[2] * ev[2]);
  float inv = 1.f / (len + 1e-12f);
  float x = ev[0] * inv, y = ev[1] * inv, z = ev[2] * inv;
  const float c1 = 1.7320508075688772f;   // sqrt(3)
  const float c2 = 3.872983346207417f;    // sqrt(15)
  int p = atomicAdd(&cursor[dst], 1);
  int si = rowptr[dst] + p;
  f16* she = sh_s + (size_t)si * SHSTR;
  she[0] = (f16)1.f;
  she[1] = (f16)(c1 * x);
  she[2] = (f16)(c1 * y);
  she[3] = (f16)(c1 * z);
  she[4] = (f16)(c2 * x * y);
  she[5] = (f16)(c2 * y * z);
  she[6] = (f16)(1.1180339887498949f * (3.f * z * z - 1.f));  // sqrt(5)/2
  she[7] = (f16)(c2 * x * z);
  she[8] = (f16)(1.9364916731037085f * (x * x - y * y));      // sqrt(15)/2
  she[9] = (f16)0.f;
  *(int*)(she + 10) = src;            // src bits in slots 10-11 (4B-aligned)
  she[12] = (f16)0.f; she[13] = (f16)0.f; she[14] = (f16)0.f; she[15] = (f16)0.f;
  lens_s[si] = len;
}

// ---------------- merged per-layer weight prep ----------------
__global__ void prep_kernel(const float* __restrict__ Wtp_l,
                            const float* __restrict__ Wself_l,
                            const float* __restrict__ Wskip_l,
                            const float* __restrict__ r2l,
                            f16* __restrict__ Wtp16,
                            f16* __restrict__ WselfT16,
                            f16* __restrict__ Bcat,
                            f16* __restrict__ r2h)
{
  int b = blockIdx.x, t = threadIdx.x;
  if (b < KTP) {
    int i = b * 256 + t;
    Wtp16[i] = (f16)Wtp_l[i];
  } else if (b < KTP + 256) {
    int n = b - KTP;
    WselfT16[(size_t)n * HD + t] = (f16)(Wself_l[(size_t)t * HD + n] * 0.28867513459481287f);
  } else if (b < KTP + 512) {
    int rho = b - KTP - 256;            // physical (permuted) Bcat row
    int pcol = perm64(rho);             // true column it holds
    Bcat[(size_t)rho * KTOT + KTP + t] = (f16)Wskip_l[(size_t)t * HD + pcol];
  } else {
    int rho = b - KTP - 512;
    if (t < KR2) {
      int p = perm64(rho);
      r2h[(size_t)rho * KR2 + t] = (t < RHID) ? (f16)r2l[(size_t)t * HD + p] : (f16)0.f;
    }
  }
}

// -------- embed conversions --------
__global__ void convert_x_kernel(const float* __restrict__ x, f16* __restrict__ xh)
{
  int i = blockIdx.x * 2 + (threadIdx.x >> 7);
  int k = threadIdx.x & 127;
  xh[(size_t)i * KEMB + k] = (i < NNODE && k < DIN) ? (f16)x[(size_t)i * DIN + k] : (f16)0.f;
}

__global__ void convert_wemb_kernel(const float* __restrict__ Wemb, f16* __restrict__ WembT16)
{
  int n = blockIdx.x, k = threadIdx.x;
  WembT16[(size_t)n * KEMB + k] = (k < DIN) ? (f16)Wemb[(size_t)k * HD + n] : (f16)0.f;
}

// small MFMA GEMM: C[M][ldc] = A[M][K] @ B^T, B n-major [N][K].
// permRows: store output row r at physical row inv_perm64(r) (for permuted Bcat).
__global__ __launch_bounds__(256) void gemm_nt_kernel(
    const f16* __restrict__ A, const f16* __restrict__ B,
    f16* __restrict__ C, int K, int ldc, int permRows)
{
  __shared__ __align__(16) f16 As[4][64][8];
  __shared__ __align__(16) f16 Bs[4][128][8];
  int t = threadIdx.x;
  int lane = t & 63, w = t >> 6;
  int row0 = blockIdx.x * 64;
  int n0 = blockIdx.y * 128;
  f32x4 acc[2][4];
#pragma unroll
  for (int i = 0; i < 2; ++i)
#pragma unroll
    for (int j = 0; j < 4; ++j) acc[i][j] = (f32x4){0.f, 0.f, 0.f, 0.f};
  int mq = (w & 1) * 32, nq = (w >> 1) * 64;
  for (int k0 = 0; k0 < K; k0 += 32) {
    {
      int row = t & 63, cc = t >> 6;
      *(uint4*)&As[cc][row][0] = *(const uint4*)(A + (size_t)(row0 + row) * K + k0 + cc * 8);
    }
#pragma unroll
    for (int u = 0; u < 2; ++u) {
      int idx = t + u * 256;
      int ch = idx >> 7, nn = idx & 127;
      *(uint4*)&Bs[ch][nn][0] = *(const uint4*)(B + (size_t)(n0 + nn) * K + k0 + ch * 8);
    }
    __syncthreads();
    int q = lane >> 4, r = lane & 15;
    f16x8 af[2], bfr[4];
#pragma unroll
    for (int i = 0; i < 2; ++i) af[i] = *(const f16x8*)&As[q][mq + i * 16 + r][0];
#pragma unroll
    for (int j = 0; j < 4; ++j) bfr[j] = *(const f16x8*)&Bs[q][nq + j * 16 + r][0];
#pragma unroll
    for (int i = 0; i < 2; ++i)
#pragma unroll
      for (int j = 0; j < 4; ++j)
        acc[i][j] = __builtin_amdgcn_mfma_f32_16x16x32_f16(af[i], bfr[j], acc[i][j], 0, 0, 0);
    __syncthreads();
  }
  int q4 = ((lane >> 4)) * 4, cl = lane & 15;
#pragma unroll
  for (int i = 0; i < 2; ++i)
#pragma unroll
    for (int rr = 0; rr < 4; ++rr) {
      int row = row0 + mq + i * 16 + q4 + rr;
      int orow = permRows ? inv_perm64(row) : row;
#pragma unroll
      for (int j = 0; j < 4; ++j)
        C[(size_t)orow * ldc + n0 + nq + j * 16 + cl] = (f16)acc[i][j][rr];
    }
}

// ------- radial[e,c] = (silu(emb@r1+b1)@r2)[e,c], dense, coalesced f16x4 stores -------
#define RHSTR 136   // rhA stride (272 B)
__global__ __launch_bounds__(256) void radial_kernel(
    const float* __restrict__ lens_s,
    const float* __restrict__ r1l, const float* __restrict__ b1l,
    const f16* __restrict__ r2h, f16* __restrict__ rad)
{
  __shared__ float r1s[NBASIS * RHID];
  __shared__ float b1s[RHID];
  __shared__ float lensL[64];
  __shared__ float embs[64][11];
  __shared__ __align__(16) f16 rhA[64 * RHSTR];
  int t = threadIdx.x;
  int lane = t & 63, w = t >> 6;
  int r = lane & 15, q = lane >> 4;
  int e0 = blockIdx.x * 64;

  if (t < 64) lensL[t] = lens_s[e0 + t];
  for (int idx = t; idx < NBASIS * RHID; idx += 256) r1s[idx] = r1l[idx];
  if (t < RHID) b1s[t] = b1l[t];
  __syncthreads();

  // issue B-frag loads early
  int n0w = w * 64;
  f16x8 bfr[4][4];
#pragma unroll
  for (int j = 0; j < 4; ++j)
#pragma unroll
    for (int ks = 0; ks < 4; ++ks)
      bfr[j][ks] = *(const f16x8*)(r2h + (size_t)(n0w + j * 16 + r) * KR2 + ks * 32 + q * 8);

  // cosine basis
  {
    const float step = 5.f / 11.f;
    const float sq = 3.1622776601683795f;   // sqrt(10)
    for (int idx = t; idx < 640; idx += 256) {
      int e = idx & 63, k = idx >> 6;
      float d = (lensL[e] - (float)(k + 1) * step) / step;
      embs[e][k] = (d > -1.f && d < 1.f) ? __cosf(1.5707963267948966f * d) * sq : 0.f;
    }
  }
  __syncthreads();

  // radial MLP -> rhA (k padded to 128)
#pragma unroll
  for (int i = 0; i < 4; ++i) {
    int e = lane;
    int g = i * 4 + w;
    f16x8 v;
#pragma unroll
    for (int kk = 0; kk < 8; ++kk) {
      int k = g * 8 + kk;
      float s = 0.f;
      if (k < RHID) {
        s = b1s[k];
#pragma unroll
        for (int jj = 0; jj < NBASIS; ++jj) s += embs[e][jj] * r1s[jj * RHID + k];
        s = __fdividef(s, 1.f + __expf(-s));
      }
      v[kk] = (f16)s;
    }
    *(f16x8*)&rhA[e * RHSTR + g * 8] = v;
  }
  __syncthreads();

  // MFMA: radial[64,256] = rh[64,128] @ r2h_perm^T ; wave w -> true cols w*64..
  f32x4 acc[4][4];
#pragma unroll
  for (int i = 0; i < 4; ++i)
#pragma unroll
    for (int j = 0; j < 4; ++j) acc[i][j] = (f32x4){0.f, 0.f, 0.f, 0.f};
#pragma unroll
  for (int ks = 0; ks < 4; ++ks) {
    f16x8 af[4];
#pragma unroll
    for (int i = 0; i < 4; ++i)
      af[i] = *(const f16x8*)&rhA[(i * 16 + r) * RHSTR + ks * 32 + q * 8];
#pragma unroll
    for (int i = 0; i < 4; ++i)
#pragma unroll
      for (int j = 0; j < 4; ++j)
        acc[i][j] = __builtin_amdgcn_mfma_f32_16x16x32_f16(af[i], bfr[j][ks], acc[i][j], 0, 0, 0);
  }

  // stores: MFMA n-index j*16+r computed true col r*4+j -> pack j as f16x4, coalesced
#pragma unroll
  for (int i = 0; i < 4; ++i)
#pragma unroll
    for (int rr = 0; rr < 4; ++rr) {
      int m = i * 16 + q * 4 + rr;
      f16x4 o;
#pragma unroll
      for (int j = 0; j < 4; ++j) o[j] = (f16)acc[i][j][rr];
      *(f16x4*)(rad + (size_t)(e0 + m) * HD + n0w + r * 4) = o;
    }
}

// ------- gather: T[n,a,c] = sum_{e->n} sh[e,a] * rad[e,c] * h[src_e,c] -------
__global__ __launch_bounds__(256) void gather2_kernel(
    const int* __restrict__ rowptr, const f16* __restrict__ rad,
    const f16* __restrict__ h, const f16* __restrict__ sh_s,
    f16* __restrict__ T)
{
  int t = threadIdx.x;
  int half = t >> 7, lc = t & 127;
  int base = blockIdx.x * 8;
  for (int s = 0; s < 4; ++s) {
    int n = base + s * 2 + half;
    int beg = rowptr[n], end = rowptr[n + 1];
    float a0[NSH], a1[NSH];
#pragma unroll
    for (int a = 0; a < NSH; ++a) { a0[a] = 0.f; a1[a] = 0.f; }
    for (int j = beg; j < end; ++j) {
      const f16* she = sh_s + (size_t)j * SHSTR;
      f16x8 s8 = *(const f16x8*)she;
      float s8v = (float)she[8];
      int src = *(const int*)(she + 10);
      f16x2 rv = *(const f16x2*)(rad + (size_t)j * HD + 2 * lc);
      f16x2 hv = *(const f16x2*)(h + (size_t)src * HD + 2 * lc);
      float h0 = (float)rv[0] * (float)hv[0];
      float h1 = (float)rv[1] * (float)hv[1];
#pragma unroll
      for (int a = 0; a < 8; ++a) {
        float sv = (float)s8[a];
        a0[a] += sv * h0; a1[a] += sv * h1;
      }
      a0[8] += s8v * h0; a1[8] += s8v * h1;
    }
    f16* Tn = T + (size_t)n * KTP + 2 * lc;
#pragma unroll
    for (int a = 0; a < NSH; ++a) {
      f16x2 o; o[0] = (f16)a0[a]; o[1] = (f16)a1[a];
      *(f16x2*)(Tn + a * HD) = o;
    }
  }
}

// ------- split-K MFMA GEMM, BARRIER-FREE: fragments loaded straight from global -------
// No LDS, no __syncthreads => no vmcnt(0) barrier drain; each wave is an
// independent pipeline the compiler can software-pipeline with partial vmcnt.
// Sector-friendly: per fragment-set the wave's 64 lanes (16 rows x 4 k-chunks)
// cover 16 rows x 64 contiguous bytes. Intra-block A/B row sharing hits L1.
#define GBM 64
#define GBN 128
__global__ __launch_bounds__(256) void gemm_splitk_kernel(
    const f16* __restrict__ A1,   // T [MPAD][2304]
    const f16* __restrict__ A2,   // h [MPAD][256]
    const f16* __restrict__ B,    // Bcat [256][2560] (n-major, perm64 rows)
    float* __restrict__ P)
{
  int t = threadIdx.x;
  int lane = t & 63, w = t >> 6;
  int kc = blockIdx.x;
  int row0 = blockIdx.y * GBM;
  int n0 = blockIdx.z * GBN;
  int mq = (w & 1) * 32, nq = (w >> 1) * 64;
  int q = lane >> 4, r = lane & 15;
  f32x4 acc[2][4];
#pragma unroll
  for (int i = 0; i < 2; ++i)
#pragma unroll
    for (int j = 0; j < 4; ++j) acc[i][j] = (f32x4){0.f, 0.f, 0.f, 0.f};
  int kbeg = kc * KCH;

  const f16* arow0 = A1 + (size_t)(row0 + mq + r) * KTP;        // +i*16*KTP
  const f16* arow0h = A2 + (size_t)(row0 + mq + r) * HD;
  const f16* brow0 = B + (size_t)(n0 + nq + r) * KTOT;          // +j*16*KTOT

#pragma unroll 2
  for (int k0 = kbeg; k0 < kbeg + KCH; k0 += 32) {
    f16x8 af[2], bfr[4];
    if (k0 < KTP) {
#pragma unroll
      for (int i = 0; i < 2; ++i)
        af[i] = *(const f16x8*)(arow0 + (size_t)i * 16 * KTP + k0 + q * 8);
    } else {
#pragma unroll
      for (int i = 0; i < 2; ++i)
        af[i] = *(const f16x8*)(arow0h + (size_t)i * 16 * HD + (k0 - KTP) + q * 8);
    }
#pragma unroll
    for (int j = 0; j < 4; ++j)
      bfr[j] = *(const f16x8*)(brow0 + (size_t)j * 16 * KTOT + k0 + q * 8);
#pragma unroll
    for (int i = 0; i < 2; ++i)
#pragma unroll
      for (int j = 0; j < 4; ++j)
        acc[i][j] = __builtin_amdgcn_mfma_f32_16x16x32_f16(af[i], bfr[j], acc[i][j], 0, 0, 0);
  }
  // thread-canonical slab layout: region [8192] floats, slab s=(i*4+j) holds
  // 256 threads x f32x4 contiguous -> fully coalesced
  float* Pb = P + ((size_t)(blockIdx.z * NRT + blockIdx.y) * SPLITK + kc) * 8192;
#pragma unroll
  for (int i = 0; i < 2; ++i)
#pragma unroll
    for (int j = 0; j < 4; ++j)
      *(f32x4*)(Pb + (i * 4 + j) * 1024 + t * 4) = acc[i][j];
}

// ------- reduce: C = gelu(sum_kc P), permuted-B f16x4 epilogue -------
__global__ __launch_bounds__(256) void reduce_kernel(const float* __restrict__ P,
                                                     f16* __restrict__ C)
{
  int t = threadIdx.x;
  int row0 = blockIdx.x * GBM;
  int n0 = blockIdx.y * GBN;
  const float* Pb = P + ((size_t)(blockIdx.y * NRT + blockIdx.x) * SPLITK) * 8192;
  f32x4 s[8];
#pragma unroll
  for (int sl = 0; sl < 8; ++sl) {
    f32x4 v = *(const f32x4*)(Pb + sl * 1024 + t * 4);
#pragma unroll
    for (int kc = 1; kc < SPLITK; ++kc)
      v += *(const f32x4*)(Pb + kc * 8192 + sl * 1024 + t * 4);
    s[sl] = v;
  }
  int lane = t & 63, w = t >> 6;
  int mq = (w & 1) * 32, nq = (w >> 1) * 64;
  int q4 = (lane >> 4) * 4, cl = lane & 15;
#pragma unroll
  for (int i = 0; i < 2; ++i)
#pragma unroll
    for (int rr = 0; rr < 4; ++rr) {
      int row = row0 + mq + i * 16 + q4 + rr;   // MPAD-padded: no guard
      f16x4 o;
#pragma unroll
      for (int j = 0; j < 4; ++j) o[j] = (f16)gelu_tanh(s[i * 4 + j][rr]);
      *(f16x4*)(C + (size_t)row * HD + n0 + nq + cl * 4) = o;
    }
}

// ---------------- node_out + graph sums ----------------
__global__ void node_out_kernel(const f16* __restrict__ h,
                                const float* __restrict__ Wout,
                                const int* __restrict__ batch,
                                float* __restrict__ sums,
                                float* __restrict__ cnts)
{
  int n = blockIdx.x * 4 + (threadIdx.x >> 6);
  int lane = threadIdx.x & 63;
  if (n >= NNODE) return;
  float s = 0.f;
#pragma unroll
  for (int t = 0; t < 4; ++t) {
    int c = lane + t * 64;
    s += (float)h[(size_t)n * HD + c] * Wout[c];
  }
#pragma unroll
  for (int off = 32; off > 0; off >>= 1) s += __shfl_down(s, off);
  if (lane == 0) {
    int g = batch[n];
    atomicAdd(&sums[g], s);
    atomicAdd(&cnts[g], 1.f);
  }
}

__global__ void finalize_kernel(const float* __restrict__ sums,
                                const float* __restrict__ cnts,
                                float* __restrict__ out)
{
  int g = threadIdx.x;
  if (g < NGRAPH) out[g] = sums[g] / fmaxf(cnts[g], 1.f);
}

// ---------------- host launch ----------------
extern "C" void kernel_launch(void* const* d_in, const int* in_sizes, int n_in,
                              void* d_out, int out_size, void* d_ws, size_t ws_size,
                              hipStream_t stream)
{
  (void)in_sizes; (void)n_in; (void)out_size;
  const float* x     = (const float*)d_in[0];
  const float* pos   = (const float*)d_in[1];
  const float* shift = (const float*)d_in[2];
  const float* lat   = (const float*)d_in[3];
  const float* Wemb  = (const float*)d_in[4];
  const float* r1    = (const float*)d_in[5];
  const float* b1    = (const float*)d_in[6];
  const float* r2    = (const float*)d_in[7];
  const float* Wtp   = (const float*)d_in[8];
  const float* Wself = (const float*)d_in[9];
  const float* Wskip = (const float*)d_in[10];
  const float* Wout  = (const float*)d_in[11];
  const int*   eidx  = (const int*)d_in[12];
  const int*   batch = (const int*)d_in[13];
  float* out = (float*)d_out;

  char* ws = (char*)d_ws;
  size_t off = 0;
  auto alloc = [&](size_t bytes) -> char* {
    char* p = ws + off;
    off += (bytes + 255) & ~(size_t)255;
    return p;
  };
  f16*   sh_s    = (f16*)alloc((size_t)NEDGE * SHSTR * 2);      //   7.68 MB
  float* lens_s  = (float*)alloc((size_t)NEDGE * 4);            //   0.96 MB
  f16*   hA      = (f16*)alloc((size_t)MPAD * HD * 2);          //  10.29 MB
  f16*   hB      = (f16*)alloc((size_t)MPAD * HD * 2);          //  10.29 MB
  f16*   T       = (f16*)alloc((size_t)MPAD * KTP * 2);         //  92.60 MB
  f16*   rad     = (f16*)alloc((size_t)NEDGE * HD * 2);         // 122.88 MB
  f16*   Bcat    = (f16*)alloc((size_t)HD * KTOT * 2);          //   1.31 MB
  f16*   r2h     = (f16*)alloc((size_t)HD * KR2 * 2);           //   64 KB
  f16*   Wtp16   = (f16*)alloc((size_t)KTP * HD * 2);           //   1.18 MB
  f16*   WselfT16= (f16*)alloc((size_t)HD * HD * 2);            //   0.13 MB
  int*   rowptr  = (int*)alloc((size_t)(NNODE + 1) * 4);
  int*   deg     = (int*)alloc((size_t)NNODE * 4);
  int*   cursor  = (int*)alloc((size_t)NNODE * 4);
  float* sums    = (float*)alloc((size_t)NGRAPH * 4);
  float* cnts    = (float*)alloc((size_t)NGRAPH * 4);
  if (off > ws_size) return;  // ~247.7 MB

  // unions into rad (dead at those phases):
  f16*   xh      = rad;                              // embed phase
  f16*   WembT16 = rad + (size_t)MPAD * KEMB;
  float* P       = (float*)rad;                      // split-K partials (82.3 MB), after gather2

  hipMemsetAsync(deg, 0, (size_t)NNODE * 4, stream);
  hipMemsetAsync(cursor, 0, (size_t)NNODE * 4, stream);
  hipMemsetAsync(sums, 0, (size_t)NGRAPH * 4, stream);
  hipMemsetAsync(cnts, 0, (size_t)NGRAPH * 4, stream);

  const int EB = (NEDGE + 255) / 256;
  deg_hist_kernel<<<EB, 256, 0, stream>>>(eidx, deg);
  scan_kernel<<<1, 256, 0, stream>>>(deg, rowptr);
  edge_geom_kernel<<<EB, 256, 0, stream>>>(pos, shift, lat, eidx, batch,
                                           rowptr, cursor, sh_s, lens_s);

  // h0 = x @ W_embed via MFMA (no row permutation)
  convert_x_kernel<<<MPAD / 2, 256, 0, stream>>>(x, xh);
  convert_wemb_kernel<<<HD, KEMB, 0, stream>>>(Wemb, WembT16);
  {
    dim3 eg(MPAD / 64, HD / 128);
    gemm_nt_kernel<<<eg, 256, 0, stream>>>(xh, WembT16, hA, KEMB, HD, 0);
  }

  f16* hcur = hA;
  f16* hnxt = hB;
  dim3 ggrid(SPLITK, NRT, 2);              // 2512 blocks, 9.8/CU
  dim3 rgrid(NRT, 2);                      // 628 blocks
  dim3 wgrid(HD / 64, KTP / 128);          // (4, 18)
  for (int l = 0; l < NLAYER; ++l) {
    const float* r1l = r1 + (size_t)l * NBASIS * RHID;
    const float* b1l = b1 + (size_t)l * RHID;
    const float* r2l = r2 + (size_t)l * RHID * HD;
    const float* Wtp_l = Wtp + (size_t)l * NSH * HD * HD;
    const float* Wself_l = Wself + (size_t)l * HD * HD;
    const float* Wskip_l = Wskip + (size_t)l * HD * HD;

    prep_kernel<<<KTP + 512 + 256, 256, 0, stream>>>(Wtp_l, Wself_l, Wskip_l, r2l,
                                                     Wtp16, WselfT16, Bcat, r2h);
    gemm_nt_kernel<<<wgrid, 256, 0, stream>>>(WselfT16, Wtp16, Bcat, HD, KTOT, 1);

    radial_kernel<<<NEDGE / 64, 256, 0, stream>>>(lens_s, r1l, b1l, r2h, rad);
    gather2_kernel<<<NNODE / 8, 256, 0, stream>>>(rowptr, rad, hcur, sh_s, T);
    gemm_splitk_kernel<<<ggrid, 256, 0, stream>>>(T, hcur, Bcat, P);
    reduce_kernel<<<rgrid, 256, 0, stream>>>(P, hnxt);
    f16* tmp = hcur; hcur = hnxt; hnxt = tmp;
  }

  node_out_kernel<<<NNODE / 4, 256, 0, stream>>>(hcur, Wout, batch, sums, cnts);
  finalize_kernel<<<1, 256, 0, stream>>>(sums, cnts, out);
}

// Round 13
// 948.421 us; speedup vs baseline: 1.2212x; 1.2212x over previous
//
#include <hip/hip_runtime.h>
#include <hip/hip_bf16.h>
#include <cstddef>
#include <cstdint>

#define NNODE  20000
#define MPAD   20096        // 314*64
#define NEDGE  240000
#define NGRAPH 200
#define DIN    118
#define HD     256
#define NBASIS 10
#define RHID   100
#define NLAYER 3
#define NSH    9
#define SHSTR  16           // sh row stride in f16 (32 B); [8]=Y8, [10..11]=src bits
#define KTP    (NSH * HD)   // 2304
#define KTOT   (KTP + HD)   // 2560
#define KR2    128          // padded radial K
#define KEMB   128          // padded embed K (118 -> 128)
#define SPLITK 4
#define KCH    (KTOT / SPLITK)   // 640
#define NRT    (MPAD / 64)       // 314 row tiles

typedef _Float16 f16;
typedef _Float16 f16x2 __attribute__((ext_vector_type(2)));
typedef _Float16 f16x4 __attribute__((ext_vector_type(4)));
typedef _Float16 f16x8 __attribute__((ext_vector_type(8)));
typedef float    f32x4 __attribute__((ext_vector_type(4)));

__device__ __forceinline__ float gelu_tanh(float v) {
  float v3 = v * v * v;
  return 0.5f * v * (1.f + tanhf(0.7978845608028654f * (v + 0.044715f * v3)));
}

// within 64-group: physical row rho holds true column perm(rho)
__device__ __forceinline__ int perm64(int rho) {
  return (rho & ~63) | ((rho & 15) * 4 + ((rho >> 4) & 3));
}
__device__ __forceinline__ int inv_perm64(int n) {
  return (n & ~63) | (((n & 3) << 4) | ((n >> 2) & 15));
}

// ---------------- CSR build ----------------
__global__ void deg_hist_kernel(const int* __restrict__ ei, int* __restrict__ deg)
{
  int e = blockIdx.x * 256 + threadIdx.x;
  if (e >= NEDGE) return;
  atomicAdd(&deg[ei[NEDGE + e]], 1);
}

__global__ void scan_kernel(const int* __restrict__ deg, int* __restrict__ rowptr)
{
  __shared__ int part[256];
  int t = threadIdx.x;
  const int chunk = (NNODE + 255) / 256;
  int start = t * chunk;
  int end = min(start + chunk, NNODE);
  int s = 0;
  for (int i = start; i < end; ++i) s += deg[i];
  part[t] = s;
  __syncthreads();
  for (int off = 1; off < 256; off <<= 1) {
    int v = (t >= off) ? part[t - off] : 0;
    __syncthreads();
    part[t] += v;
    __syncthreads();
  }
  int run = (t == 0) ? 0 : part[t - 1];
  for (int i = start; i < end; ++i) { rowptr[i] = run; run += deg[i]; }
  if (t == 255) rowptr[NNODE] = run;
}

// -------- edge geometry + scatter into CSR (dst-sorted) position --------
__global__ void edge_geom_kernel(const float* __restrict__ pos,
                                 const float* __restrict__ shift,
                                 const float* __restrict__ lat,
                                 const int* __restrict__ ei,
                                 const int* __restrict__ batch,
                                 const int* __restrict__ rowptr,
                                 int* __restrict__ cursor,
                                 f16* __restrict__ sh_s,
                                 float* __restrict__ lens_s)
{
  int e = blockIdx.x * 256 + threadIdx.x;
  if (e >= NEDGE) return;
  int src = ei[e];
  int dst = ei[NEDGE + e];
  int b = batch[src];
  const float* L = lat + (size_t)b * 9;
  float s0 = shift[e * 3 + 0], s1 = shift[e * 3 + 1], s2 = shift[e * 3 + 2];
  float ev[3];
#pragma unroll
  for (int j = 0; j < 3; ++j)
    ev[j] = pos[dst * 3 + j] - pos[src * 3 + j] + s0 * L[j] + s1 * L[3 + j] + s2 * L[6 + j];
  float len = sqrtf(ev[0] * ev[0] + ev[1] * ev[1] + ev[2] * ev[2]);
  float inv = 1.f / (len + 1e-12f);
  float x = ev[0] * inv, y = ev[1] * inv, z = ev[2] * inv;
  const float c1 = 1.7320508075688772f;   // sqrt(3)
  const float c2 = 3.872983346207417f;    // sqrt(15)
  int p = atomicAdd(&cursor[dst], 1);
  int si = rowptr[dst] + p;
  f16* she = sh_s + (size_t)si * SHSTR;
  she[0] = (f16)1.f;
  she[1] = (f16)(c1 * x);
  she[2] = (f16)(c1 * y);
  she[3] = (f16)(c1 * z);
  she[4] = (f16)(c2 * x * y);
  she[5] = (f16)(c2 * y * z);
  she[6] = (f16)(1.1180339887498949f * (3.f * z * z - 1.f));  // sqrt(5)/2
  she[7] = (f16)(c2 * x * z);
  she[8] = (f16)(1.9364916731037085f * (x * x - y * y));      // sqrt(15)/2
  she[9] = (f16)0.f;
  *(int*)(she + 10) = src;            // src bits in slots 10-11 (4B-aligned)
  she[12] = (f16)0.f; she[13] = (f16)0.f; she[14] = (f16)0.f; she[15] = (f16)0.f;
  lens_s[si] = len;
}

// ---------------- merged per-layer weight prep ----------------
__global__ void prep_kernel(const float* __restrict__ Wtp_l,
                            const float* __restrict__ Wself_l,
                            const float* __restrict__ Wskip_l,
                            const float* __restrict__ r2l,
                            f16* __restrict__ Wtp16,
                            f16* __restrict__ WselfT16,
                            f16* __restrict__ Bcat,
                            f16* __restrict__ r2h)
{
  int b = blockIdx.x, t = threadIdx.x;
  if (b < KTP) {
    int i = b * 256 + t;
    Wtp16[i] = (f16)Wtp_l[i];
  } else if (b < KTP + 256) {
    int n = b - KTP;
    WselfT16[(size_t)n * HD + t] = (f16)(Wself_l[(size_t)t * HD + n] * 0.28867513459481287f);
  } else if (b < KTP + 512) {
    int rho = b - KTP - 256;            // physical (permuted) Bcat row
    int pcol = perm64(rho);             // true column it holds
    Bcat[(size_t)rho * KTOT + KTP + t] = (f16)Wskip_l[(size_t)t * HD + pcol];
  } else {
    int rho = b - KTP - 512;
    if (t < KR2) {
      int p = perm64(rho);
      r2h[(size_t)rho * KR2 + t] = (t < RHID) ? (f16)r2l[(size_t)t * HD + p] : (f16)0.f;
    }
  }
}

// -------- embed conversions --------
__global__ void convert_x_kernel(const float* __restrict__ x, f16* __restrict__ xh)
{
  int i = blockIdx.x * 2 + (threadIdx.x >> 7);
  int k = threadIdx.x & 127;
  xh[(size_t)i * KEMB + k] = (i < NNODE && k < DIN) ? (f16)x[(size_t)i * DIN + k] : (f16)0.f;
}

__global__ void convert_wemb_kernel(const float* __restrict__ Wemb, f16* __restrict__ WembT16)
{
  int n = blockIdx.x, k = threadIdx.x;
  WembT16[(size_t)n * KEMB + k] = (k < DIN) ? (f16)Wemb[(size_t)k * HD + n] : (f16)0.f;
}

// small MFMA GEMM: C[M][ldc] = A[M][K] @ B^T, B n-major [N][K].
// permRows: store output row r at physical row inv_perm64(r) (for permuted Bcat).
__global__ __launch_bounds__(256) void gemm_nt_kernel(
    const f16* __restrict__ A, const f16* __restrict__ B,
    f16* __restrict__ C, int K, int ldc, int permRows)
{
  __shared__ __align__(16) f16 As[4][64][8];
  __shared__ __align__(16) f16 Bs[4][128][8];
  int t = threadIdx.x;
  int lane = t & 63, w = t >> 6;
  int row0 = blockIdx.x * 64;
  int n0 = blockIdx.y * 128;
  f32x4 acc[2][4];
#pragma unroll
  for (int i = 0; i < 2; ++i)
#pragma unroll
    for (int j = 0; j < 4; ++j) acc[i][j] = (f32x4){0.f, 0.f, 0.f, 0.f};
  int mq = (w & 1) * 32, nq = (w >> 1) * 64;
  for (int k0 = 0; k0 < K; k0 += 32) {
    {
      int row = t & 63, cc = t >> 6;
      *(uint4*)&As[cc][row][0] = *(const uint4*)(A + (size_t)(row0 + row) * K + k0 + cc * 8);
    }
#pragma unroll
    for (int u = 0; u < 2; ++u) {
      int idx = t + u * 256;
      int ch = idx >> 7, nn = idx & 127;
      *(uint4*)&Bs[ch][nn][0] = *(const uint4*)(B + (size_t)(n0 + nn) * K + k0 + ch * 8);
    }
    __syncthreads();
    int q = lane >> 4, r = lane & 15;
    f16x8 af[2], bfr[4];
#pragma unroll
    for (int i = 0; i < 2; ++i) af[i] = *(const f16x8*)&As[q][mq + i * 16 + r][0];
#pragma unroll
    for (int j = 0; j < 4; ++j) bfr[j] = *(const f16x8*)&Bs[q][nq + j * 16 + r][0];
#pragma unroll
    for (int i = 0; i < 2; ++i)
#pragma unroll
      for (int j = 0; j < 4; ++j)
        acc[i][j] = __builtin_amdgcn_mfma_f32_16x16x32_f16(af[i], bfr[j], acc[i][j], 0, 0, 0);
    __syncthreads();
  }
  int q4 = ((lane >> 4)) * 4, cl = lane & 15;
#pragma unroll
  for (int i = 0; i < 2; ++i)
#pragma unroll
    for (int rr = 0; rr < 4; ++rr) {
      int row = row0 + mq + i * 16 + q4 + rr;
      int orow = permRows ? inv_perm64(row) : row;
#pragma unroll
      for (int j = 0; j < 4; ++j)
        C[(size_t)orow * ldc + n0 + nq + j * 16 + cl] = (f16)acc[i][j][rr];
    }
}

// ------- radial[e,c] = (silu(emb@r1+b1)@r2)[e,c], dense, coalesced f16x4 stores -------
#define RHSTR 136   // rhA stride (272 B)
__global__ __launch_bounds__(256) void radial_kernel(
    const float* __restrict__ lens_s,
    const float* __restrict__ r1l, const float* __restrict__ b1l,
    const f16* __restrict__ r2h, f16* __restrict__ rad)
{
  __shared__ float r1s[NBASIS * RHID];
  __shared__ float b1s[RHID];
  __shared__ float lensL[64];
  __shared__ float embs[64][11];
  __shared__ __align__(16) f16 rhA[64 * RHSTR];
  int t = threadIdx.x;
  int lane = t & 63, w = t >> 6;
  int r = lane & 15, q = lane >> 4;
  int e0 = blockIdx.x * 64;

  if (t < 64) lensL[t] = lens_s[e0 + t];
  for (int idx = t; idx < NBASIS * RHID; idx += 256) r1s[idx] = r1l[idx];
  if (t < RHID) b1s[t] = b1l[t];
  __syncthreads();

  // issue B-frag loads early
  int n0w = w * 64;
  f16x8 bfr[4][4];
#pragma unroll
  for (int j = 0; j < 4; ++j)
#pragma unroll
    for (int ks = 0; ks < 4; ++ks)
      bfr[j][ks] = *(const f16x8*)(r2h + (size_t)(n0w + j * 16 + r) * KR2 + ks * 32 + q * 8);

  // cosine basis
  {
    const float step = 5.f / 11.f;
    const float sq = 3.1622776601683795f;   // sqrt(10)
    for (int idx = t; idx < 640; idx += 256) {
      int e = idx & 63, k = idx >> 6;
      float d = (lensL[e] - (float)(k + 1) * step) / step;
      embs[e][k] = (d > -1.f && d < 1.f) ? __cosf(1.5707963267948966f * d) * sq : 0.f;
    }
  }
  __syncthreads();

  // radial MLP -> rhA (k padded to 128)
#pragma unroll
  for (int i = 0; i < 4; ++i) {
    int e = lane;
    int g = i * 4 + w;
    f16x8 v;
#pragma unroll
    for (int kk = 0; kk < 8; ++kk) {
      int k = g * 8 + kk;
      float s = 0.f;
      if (k < RHID) {
        s = b1s[k];
#pragma unroll
        for (int jj = 0; jj < NBASIS; ++jj) s += embs[e][jj] * r1s[jj * RHID + k];
        s = __fdividef(s, 1.f + __expf(-s));
      }
      v[kk] = (f16)s;
    }
    *(f16x8*)&rhA[e * RHSTR + g * 8] = v;
  }
  __syncthreads();

  // MFMA: radial[64,256] = rh[64,128] @ r2h_perm^T ; wave w -> true cols w*64..
  f32x4 acc[4][4];
#pragma unroll
  for (int i = 0; i < 4; ++i)
#pragma unroll
    for (int j = 0; j < 4; ++j) acc[i][j] = (f32x4){0.f, 0.f, 0.f, 0.f};
#pragma unroll
  for (int ks = 0; ks < 4; ++ks) {
    f16x8 af[4];
#pragma unroll
    for (int i = 0; i < 4; ++i)
      af[i] = *(const f16x8*)&rhA[(i * 16 + r) * RHSTR + ks * 32 + q * 8];
#pragma unroll
    for (int i = 0; i < 4; ++i)
#pragma unroll
      for (int j = 0; j < 4; ++j)
        acc[i][j] = __builtin_amdgcn_mfma_f32_16x16x32_f16(af[i], bfr[j][ks], acc[i][j], 0, 0, 0);
  }

  // stores: MFMA n-index j*16+r computed true col r*4+j -> pack j as f16x4, coalesced
#pragma unroll
  for (int i = 0; i < 4; ++i)
#pragma unroll
    for (int rr = 0; rr < 4; ++rr) {
      int m = i * 16 + q * 4 + rr;
      f16x4 o;
#pragma unroll
      for (int j = 0; j < 4; ++j) o[j] = (f16)acc[i][j][rr];
      *(f16x4*)(rad + (size_t)(e0 + m) * HD + n0w + r * 4) = o;
    }
}

// ------- gather: T[n,a,c] = sum_{e->n} sh[e,a] * rad[e,c] * h[src_e,c] -------
// 2-edge unroll (2x loads in flight), 5000 blocks (2 node-phases each)
__global__ __launch_bounds__(256) void gather2_kernel(
    const int* __restrict__ rowptr, const f16* __restrict__ rad,
    const f16* __restrict__ h, const f16* __restrict__ sh_s,
    f16* __restrict__ T)
{
  int t = threadIdx.x;
  int half = t >> 7, lc = t & 127;
  int base = blockIdx.x * 4;
  for (int s = 0; s < 2; ++s) {
    int n = base + s * 2 + half;
    int beg = rowptr[n], end = rowptr[n + 1];
    float a0[NSH], a1[NSH];
#pragma unroll
    for (int a = 0; a < NSH; ++a) { a0[a] = 0.f; a1[a] = 0.f; }
    int j = beg;
    for (; j + 2 <= end; j += 2) {
      const f16* she0 = sh_s + (size_t)j * SHSTR;
      const f16* she1 = she0 + SHSTR;
      f16x8 s80 = *(const f16x8*)she0;
      f16x8 s81 = *(const f16x8*)she1;
      float s8v0 = (float)she0[8];
      float s8v1 = (float)she1[8];
      int src0 = *(const int*)(she0 + 10);
      int src1 = *(const int*)(she1 + 10);
      f16x2 rv0 = *(const f16x2*)(rad + (size_t)j * HD + 2 * lc);
      f16x2 rv1 = *(const f16x2*)(rad + (size_t)(j + 1) * HD + 2 * lc);
      f16x2 hv0 = *(const f16x2*)(h + (size_t)src0 * HD + 2 * lc);
      f16x2 hv1 = *(const f16x2*)(h + (size_t)src1 * HD + 2 * lc);
      float p00 = (float)rv0[0] * (float)hv0[0];
      float p01 = (float)rv0[1] * (float)hv0[1];
      float p10 = (float)rv1[0] * (float)hv1[0];
      float p11 = (float)rv1[1] * (float)hv1[1];
#pragma unroll
      for (int a = 0; a < 8; ++a) {
        float sv0 = (float)s80[a], sv1 = (float)s81[a];
        a0[a] += sv0 * p00 + sv1 * p10;
        a1[a] += sv0 * p01 + sv1 * p11;
      }
      a0[8] += s8v0 * p00 + s8v1 * p10;
      a1[8] += s8v0 * p01 + s8v1 * p11;
    }
    if (j < end) {
      const f16* she = sh_s + (size_t)j * SHSTR;
      f16x8 s8 = *(const f16x8*)she;
      float s8v = (float)she[8];
      int src = *(const int*)(she + 10);
      f16x2 rv = *(const f16x2*)(rad + (size_t)j * HD + 2 * lc);
      f16x2 hv = *(const f16x2*)(h + (size_t)src * HD + 2 * lc);
      float p0 = (float)rv[0] * (float)hv[0];
      float p1 = (float)rv[1] * (float)hv[1];
#pragma unroll
      for (int a = 0; a < 8; ++a) {
        float sv = (float)s8[a];
        a0[a] += sv * p0; a1[a] += sv * p1;
      }
      a0[8] += s8v * p0; a1[8] += s8v * p1;
    }
    f16* Tn = T + (size_t)n * KTP + 2 * lc;
#pragma unroll
    for (int a = 0; a < NSH; ++a) {
      f16x2 o; o[0] = (f16)a0[a]; o[1] = (f16)a1[a];
      *(f16x2*)(Tn + a * HD) = o;
    }
  }
}

// ------- split-K MFMA GEMM (round-11 proven: LDS staged, 98 us, 0 conflicts) -------
#define GBM 64
#define GBN 128
__global__ __launch_bounds__(256) void gemm_splitk_kernel(
    const f16* __restrict__ A1,   // T [MPAD][2304]
    const f16* __restrict__ A2,   // h [MPAD][256]
    const f16* __restrict__ B,    // Bcat [256][2560] (n-major, perm64 rows)
    float* __restrict__ P)
{
  __shared__ __align__(16) f16 As[4][GBM][8];
  __shared__ __align__(16) f16 Bs[4][GBN][8];
  int t = threadIdx.x;
  int lane = t & 63, w = t >> 6;
  int kc = blockIdx.x;
  int row0 = blockIdx.y * GBM;
  int n0 = blockIdx.z * GBN;
  f32x4 acc[2][4];
#pragma unroll
  for (int i = 0; i < 2; ++i)
#pragma unroll
    for (int j = 0; j < 4; ++j) acc[i][j] = (f32x4){0.f, 0.f, 0.f, 0.f};
  int mq = (w & 1) * 32, nq = (w >> 1) * 64;
  int kbeg = kc * KCH;

  for (int k0 = kbeg; k0 < kbeg + KCH; k0 += 32) {
    {
      int row = t & 63, cc = t >> 6;
      const f16* ga = (k0 < KTP)
          ? (A1 + (size_t)(row0 + row) * KTP + k0 + cc * 8)
          : (A2 + (size_t)(row0 + row) * HD + (k0 - KTP) + cc * 8);
      *(uint4*)&As[cc][row][0] = *(const uint4*)ga;
    }
#pragma unroll
    for (int u = 0; u < 2; ++u) {
      int idx = t + u * 256;
      int ch = idx >> 7, nn = idx & 127;
      *(uint4*)&Bs[ch][nn][0] = *(const uint4*)(B + (size_t)(n0 + nn) * KTOT + k0 + ch * 8);
    }
    __syncthreads();
    int q = lane >> 4, r = lane & 15;
    f16x8 af[2], bfr[4];
#pragma unroll
    for (int i = 0; i < 2; ++i) af[i] = *(const f16x8*)&As[q][mq + i * 16 + r][0];
#pragma unroll
    for (int j = 0; j < 4; ++j) bfr[j] = *(const f16x8*)&Bs[q][nq + j * 16 + r][0];
#pragma unroll
    for (int i = 0; i < 2; ++i)
#pragma unroll
      for (int j = 0; j < 4; ++j)
        acc[i][j] = __builtin_amdgcn_mfma_f32_16x16x32_f16(af[i], bfr[j], acc[i][j], 0, 0, 0);
    __syncthreads();
  }
  // thread-canonical slab layout: region [8192] floats, slab s=(i*4+j) holds
  // 256 threads x f32x4 contiguous -> fully coalesced
  float* Pb = P + ((size_t)(blockIdx.z * NRT + blockIdx.y) * SPLITK + kc) * 8192;
#pragma unroll
  for (int i = 0; i < 2; ++i)
#pragma unroll
    for (int j = 0; j < 4; ++j)
      *(f32x4*)(Pb + (i * 4 + j) * 1024 + t * 4) = acc[i][j];
}

// ------- reduce: C = gelu(sum_kc P), permuted-B f16x4 epilogue -------
__global__ __launch_bounds__(256) void reduce_kernel(const float* __restrict__ P,
                                                     f16* __restrict__ C)
{
  int t = threadIdx.x;
  int row0 = blockIdx.x * GBM;
  int n0 = blockIdx.y * GBN;
  const float* Pb = P + ((size_t)(blockIdx.y * NRT + blockIdx.x) * SPLITK) * 8192;
  f32x4 s[8];
#pragma unroll
  for (int sl = 0; sl < 8; ++sl) {
    f32x4 v = *(const f32x4*)(Pb + sl * 1024 + t * 4);
#pragma unroll
    for (int kc = 1; kc < SPLITK; ++kc)
      v += *(const f32x4*)(Pb + kc * 8192 + sl * 1024 + t * 4);
    s[sl] = v;
  }
  int lane = t & 63, w = t >> 6;
  int mq = (w & 1) * 32, nq = (w >> 1) * 64;
  int q4 = (lane >> 4) * 4, cl = lane & 15;
#pragma unroll
  for (int i = 0; i < 2; ++i)
#pragma unroll
    for (int rr = 0; rr < 4; ++rr) {
      int row = row0 + mq + i * 16 + q4 + rr;   // MPAD-padded: no guard
      f16x4 o;
#pragma unroll
      for (int j = 0; j < 4; ++j) o[j] = (f16)gelu_tanh(s[i * 4 + j][rr]);
      *(f16x4*)(C + (size_t)row * HD + n0 + nq + cl * 4) = o;
    }
}

// ---------------- node_out + graph sums ----------------
__global__ void node_out_kernel(const f16* __restrict__ h,
                                const float* __restrict__ Wout,
                                const int* __restrict__ batch,
                                float* __restrict__ sums,
                                float* __restrict__ cnts)
{
  int n = blockIdx.x * 4 + (threadIdx.x >> 6);
  int lane = threadIdx.x & 63;
  if (n >= NNODE) return;
  float s = 0.f;
#pragma unroll
  for (int t = 0; t < 4; ++t) {
    int c = lane + t * 64;
    s += (float)h[(size_t)n * HD + c] * Wout[c];
  }
#pragma unroll
  for (int off = 32; off > 0; off >>= 1) s += __shfl_down(s, off);
  if (lane == 0) {
    int g = batch[n];
    atomicAdd(&sums[g], s);
    atomicAdd(&cnts[g], 1.f);
  }
}

__global__ void finalize_kernel(const float* __restrict__ sums,
                                const float* __restrict__ cnts,
                                float* __restrict__ out)
{
  int g = threadIdx.x;
  if (g < NGRAPH) out[g] = sums[g] / fmaxf(cnts[g], 1.f);
}

// ---------------- host launch ----------------
extern "C" void kernel_launch(void* const* d_in, const int* in_sizes, int n_in,
                              void* d_out, int out_size, void* d_ws, size_t ws_size,
                              hipStream_t stream)
{
  (void)in_sizes; (void)n_in; (void)out_size;
  const float* x     = (const float*)d_in[0];
  const float* pos   = (const float*)d_in[1];
  const float* shift = (const float*)d_in[2];
  const float* lat   = (const float*)d_in[3];
  const float* Wemb  = (const float*)d_in[4];
  const float* r1    = (const float*)d_in[5];
  const float* b1    = (const float*)d_in[6];
  const float* r2    = (const float*)d_in[7];
  const float* Wtp   = (const float*)d_in[8];
  const float* Wself = (const float*)d_in[9];
  const float* Wskip = (const float*)d_in[10];
  const float* Wout  = (const float*)d_in[11];
  const int*   eidx  = (const int*)d_in[12];
  const int*   batch = (const int*)d_in[13];
  float* out = (float*)d_out;

  char* ws = (char*)d_ws;
  size_t off = 0;
  auto alloc = [&](size_t bytes) -> char* {
    char* p = ws + off;
    off += (bytes + 255) & ~(size_t)255;
    return p;
  };
  f16*   sh_s    = (f16*)alloc((size_t)NEDGE * SHSTR * 2);      //   7.68 MB
  float* lens_s  = (float*)alloc((size_t)NEDGE * 4);            //   0.96 MB
  f16*   hA      = (f16*)alloc((size_t)MPAD * HD * 2);          //  10.29 MB
  f16*   hB      = (f16*)alloc((size_t)MPAD * HD * 2);          //  10.29 MB
  f16*   T       = (f16*)alloc((size_t)MPAD * KTP * 2);         //  92.60 MB
  f16*   rad     = (f16*)alloc((size_t)NEDGE * HD * 2);         // 122.88 MB
  f16*   Bcat    = (f16*)alloc((size_t)HD * KTOT * 2);          //   1.31 MB
  f16*   r2h     = (f16*)alloc((size_t)HD * KR2 * 2);           //   64 KB
  f16*   Wtp16   = (f16*)alloc((size_t)KTP * HD * 2);           //   1.18 MB
  f16*   WselfT16= (f16*)alloc((size_t)HD * HD * 2);            //   0.13 MB
  int*   rowptr  = (int*)alloc((size_t)(NNODE + 1) * 4);
  int*   deg     = (int*)alloc((size_t)NNODE * 4);
  int*   cursor  = (int*)alloc((size_t)NNODE * 4);
  float* sums    = (float*)alloc((size_t)NGRAPH * 4);
  float* cnts    = (float*)alloc((size_t)NGRAPH * 4);
  if (off > ws_size) return;  // ~247.7 MB

  // unions into rad (dead at those phases):
  f16*   xh      = rad;                              // embed phase
  f16*   WembT16 = rad + (size_t)MPAD * KEMB;
  float* P       = (float*)rad;                      // split-K partials (82.3 MB), after gather2

  hipMemsetAsync(deg, 0, (size_t)NNODE * 4, stream);
  hipMemsetAsync(cursor, 0, (size_t)NNODE * 4, stream);
  hipMemsetAsync(sums, 0, (size_t)NGRAPH * 4, stream);
  hipMemsetAsync(cnts, 0, (size_t)NGRAPH * 4, stream);

  const int EB = (NEDGE + 255) / 256;
  deg_hist_kernel<<<EB, 256, 0, stream>>>(eidx, deg);
  scan_kernel<<<1, 256, 0, stream>>>(deg, rowptr);
  edge_geom_kernel<<<EB, 256, 0, stream>>>(pos, shift, lat, eidx, batch,
                                           rowptr, cursor, sh_s, lens_s);

  // h0 = x @ W_embed via MFMA (no row permutation)
  convert_x_kernel<<<MPAD / 2, 256, 0, stream>>>(x, xh);
  convert_wemb_kernel<<<HD, KEMB, 0, stream>>>(Wemb, WembT16);
  {
    dim3 eg(MPAD / 64, HD / 128);
    gemm_nt_kernel<<<eg, 256, 0, stream>>>(xh, WembT16, hA, KEMB, HD, 0);
  }

  f16* hcur = hA;
  f16* hnxt = hB;
  dim3 ggrid(SPLITK, NRT, 2);              // 2512 blocks, 9.8/CU
  dim3 rgrid(NRT, 2);                      // 628 blocks
  dim3 wgrid(HD / 64, KTP / 128);          // (4, 18)
  for (int l = 0; l < NLAYER; ++l) {
    const float* r1l = r1 + (size_t)l * NBASIS * RHID;
    const float* b1l = b1 + (size_t)l * RHID;
    const float* r2l = r2 + (size_t)l * RHID * HD;
    const float* Wtp_l = Wtp + (size_t)l * NSH * HD * HD;
    const float* Wself_l = Wself + (size_t)l * HD * HD;
    const float* Wskip_l = Wskip + (size_t)l * HD * HD;

    prep_kernel<<<KTP + 512 + 256, 256, 0, stream>>>(Wtp_l, Wself_l, Wskip_l, r2l,
                                                     Wtp16, WselfT16, Bcat, r2h);
    gemm_nt_kernel<<<wgrid, 256, 0, stream>>>(WselfT16, Wtp16, Bcat, HD, KTOT, 1);

    radial_kernel<<<NEDGE / 64, 256, 0, stream>>>(lens_s, r1l, b1l, r2h, rad);
    gather2_kernel<<<NNODE / 4, 256, 0, stream>>>(rowptr, rad, hcur, sh_s, T);
    gemm_splitk_kernel<<<ggrid, 256, 0, stream>>>(T, hcur, Bcat, P);
    reduce_kernel<<<rgrid, 256, 0, stream>>>(P, hnxt);
    f16* tmp = hcur; hcur = hnxt; hnxt = tmp;
  }

  node_out_kernel<<<NNODE / 4, 256, 0, stream>>>(hcur, Wout, batch, sums, cnts);
  finalize_kernel<<<1, 256, 0, stream>>>(sums, cnts, out);
}

// Round 14
// 850.473 us; speedup vs baseline: 1.3618x; 1.1152x over previous
//
#include <hip/hip_runtime.h>
#include <hip/hip_bf16.h>
#include <cstddef>
#include <cstdint>

#define NNODE  20000
#define MPAD   20096        // 314*64
#define NEDGE  240000
#define NGRAPH 200
#define DIN    118
#define HD     256
#define NBASIS 10
#define RHID   100
#define NLAYER 3
#define NSH    9
#define SHSTR  16           // sh row stride in f16 (32 B); [8]=Y8, [10..11]=src bits
#define KTP    (NSH * HD)   // 2304
#define KTOT   (KTP + HD)   // 2560
#define KR2    128          // padded radial K
#define KEMB   128          // padded embed K (118 -> 128)
#define SPLITK 4
#define KCH    (KTOT / SPLITK)   // 640
#define NRT    (MPAD / 64)       // 314 row tiles

typedef _Float16 f16;
typedef _Float16 f16x2 __attribute__((ext_vector_type(2)));
typedef _Float16 f16x4 __attribute__((ext_vector_type(4)));
typedef _Float16 f16x8 __attribute__((ext_vector_type(8)));
typedef float    f32x4 __attribute__((ext_vector_type(4)));

__device__ __forceinline__ float gelu_tanh(float v) {
  float v3 = v * v * v;
  return 0.5f * v * (1.f + tanhf(0.7978845608028654f * (v + 0.044715f * v3)));
}

// within 64-group: physical row rho holds true column perm(rho)
__device__ __forceinline__ int perm64(int rho) {
  return (rho & ~63) | ((rho & 15) * 4 + ((rho >> 4) & 3));
}
__device__ __forceinline__ int inv_perm64(int n) {
  return (n & ~63) | (((n & 3) << 4) | ((n >> 2) & 15));
}

// ---------------- CSR build ----------------
__global__ void deg_hist_kernel(const int* __restrict__ ei, int* __restrict__ deg)
{
  int e = blockIdx.x * 256 + threadIdx.x;
  if (e >= NEDGE) return;
  atomicAdd(&deg[ei[NEDGE + e]], 1);
}

__global__ void scan_kernel(const int* __restrict__ deg, int* __restrict__ rowptr)
{
  __shared__ int part[256];
  int t = threadIdx.x;
  const int chunk = (NNODE + 255) / 256;
  int start = t * chunk;
  int end = min(start + chunk, NNODE);
  int s = 0;
  for (int i = start; i < end; ++i) s += deg[i];
  part[t] = s;
  __syncthreads();
  for (int off = 1; off < 256; off <<= 1) {
    int v = (t >= off) ? part[t - off] : 0;
    __syncthreads();
    part[t] += v;
    __syncthreads();
  }
  int run = (t == 0) ? 0 : part[t - 1];
  for (int i = start; i < end; ++i) { rowptr[i] = run; run += deg[i]; }
  if (t == 255) rowptr[NNODE] = run;
}

// -------- edge geometry + scatter into CSR (dst-sorted) position --------
__global__ void edge_geom_kernel(const float* __restrict__ pos,
                                 const float* __restrict__ shift,
                                 const float* __restrict__ lat,
                                 const int* __restrict__ ei,
                                 const int* __restrict__ batch,
                                 const int* __restrict__ rowptr,
                                 int* __restrict__ cursor,
                                 f16* __restrict__ sh_s,
                                 float* __restrict__ lens_s)
{
  int e = blockIdx.x * 256 + threadIdx.x;
  if (e >= NEDGE) return;
  int src = ei[e];
  int dst = ei[NEDGE + e];
  int b = batch[src];
  const float* L = lat + (size_t)b * 9;
  float s0 = shift[e * 3 + 0], s1 = shift[e * 3 + 1], s2 = shift[e * 3 + 2];
  float ev[3];
#pragma unroll
  for (int j = 0; j < 3; ++j)
    ev[j] = pos[dst * 3 + j] - pos[src * 3 + j] + s0 * L[j] + s1 * L[3 + j] + s2 * L[6 + j];
  float len = sqrtf(ev[0] * ev[0] + ev[1] * ev[1] + ev[2] * ev[2]);
  float inv = 1.f / (len + 1e-12f);
  float x = ev[0] * inv, y = ev[1] * inv, z = ev[2] * inv;
  const float c1 = 1.7320508075688772f;   // sqrt(3)
  const float c2 = 3.872983346207417f;    // sqrt(15)
  int p = atomicAdd(&cursor[dst], 1);
  int si = rowptr[dst] + p;
  f16* she = sh_s + (size_t)si * SHSTR;
  she[0] = (f16)1.f;
  she[1] = (f16)(c1 * x);
  she[2] = (f16)(c1 * y);
  she[3] = (f16)(c1 * z);
  she[4] = (f16)(c2 * x * y);
  she[5] = (f16)(c2 * y * z);
  she[6] = (f16)(1.1180339887498949f * (3.f * z * z - 1.f));  // sqrt(5)/2
  she[7] = (f16)(c2 * x * z);
  she[8] = (f16)(1.9364916731037085f * (x * x - y * y));      // sqrt(15)/2
  she[9] = (f16)0.f;
  *(int*)(she + 10) = src;            // src bits in slots 10-11 (4B-aligned)
  she[12] = (f16)0.f; she[13] = (f16)0.f; she[14] = (f16)0.f; she[15] = (f16)0.f;
  lens_s[si] = len;
}

// ---------------- merged per-layer weight prep ----------------
__global__ void prep_kernel(const float* __restrict__ Wtp_l,
                            const float* __restrict__ Wself_l,
                            const float* __restrict__ Wskip_l,
                            const float* __restrict__ r2l,
                            f16* __restrict__ Wtp16,
                            f16* __restrict__ WselfT16,
                            f16* __restrict__ Bcat,
                            f16* __restrict__ r2h)
{
  int b = blockIdx.x, t = threadIdx.x;
  if (b < KTP) {
    int i = b * 256 + t;
    Wtp16[i] = (f16)Wtp_l[i];
  } else if (b < KTP + 256) {
    int n = b - KTP;
    WselfT16[(size_t)n * HD + t] = (f16)(Wself_l[(size_t)t * HD + n] * 0.28867513459481287f);
  } else if (b < KTP + 512) {
    int rho = b - KTP - 256;            // physical (permuted) Bcat row
    int pcol = perm64(rho);             // true column it holds
    Bcat[(size_t)rho * KTOT + KTP + t] = (f16)Wskip_l[(size_t)t * HD + pcol];
  } else {
    int rho = b - KTP - 512;
    if (t < KR2) {
      int p = perm64(rho);
      r2h[(size_t)rho * KR2 + t] = (t < RHID) ? (f16)r2l[(size_t)t * HD + p] : (f16)0.f;
    }
  }
}

// -------- embed conversions --------
__global__ void convert_x_kernel(const float* __restrict__ x, f16* __restrict__ xh)
{
  int i = blockIdx.x * 2 + (threadIdx.x >> 7);
  int k = threadIdx.x & 127;
  xh[(size_t)i * KEMB + k] = (i < NNODE && k < DIN) ? (f16)x[(size_t)i * DIN + k] : (f16)0.f;
}

__global__ void convert_wemb_kernel(const float* __restrict__ Wemb, f16* __restrict__ WembT16)
{
  int n = blockIdx.x, k = threadIdx.x;
  WembT16[(size_t)n * KEMB + k] = (k < DIN) ? (f16)Wemb[(size_t)k * HD + n] : (f16)0.f;
}

// small MFMA GEMM: C[M][ldc] = A[M][K] @ B^T, B n-major [N][K].
// permRows: store output row r at physical row inv_perm64(r) (for permuted Bcat).
__global__ __launch_bounds__(256) void gemm_nt_kernel(
    const f16* __restrict__ A, const f16* __restrict__ B,
    f16* __restrict__ C, int K, int ldc, int permRows)
{
  __shared__ __align__(16) f16 As[4][64][8];
  __shared__ __align__(16) f16 Bs[4][128][8];
  int t = threadIdx.x;
  int lane = t & 63, w = t >> 6;
  int row0 = blockIdx.x * 64;
  int n0 = blockIdx.y * 128;
  f32x4 acc[2][4];
#pragma unroll
  for (int i = 0; i < 2; ++i)
#pragma unroll
    for (int j = 0; j < 4; ++j) acc[i][j] = (f32x4){0.f, 0.f, 0.f, 0.f};
  int mq = (w & 1) * 32, nq = (w >> 1) * 64;
  for (int k0 = 0; k0 < K; k0 += 32) {
    {
      int row = t & 63, cc = t >> 6;
      *(uint4*)&As[cc][row][0] = *(const uint4*)(A + (size_t)(row0 + row) * K + k0 + cc * 8);
    }
#pragma unroll
    for (int u = 0; u < 2; ++u) {
      int idx = t + u * 256;
      int ch = idx >> 7, nn = idx & 127;
      *(uint4*)&Bs[ch][nn][0] = *(const uint4*)(B + (size_t)(n0 + nn) * K + k0 + ch * 8);
    }
    __syncthreads();
    int q = lane >> 4, r = lane & 15;
    f16x8 af[2], bfr[4];
#pragma unroll
    for (int i = 0; i < 2; ++i) af[i] = *(const f16x8*)&As[q][mq + i * 16 + r][0];
#pragma unroll
    for (int j = 0; j < 4; ++j) bfr[j] = *(const f16x8*)&Bs[q][nq + j * 16 + r][0];
#pragma unroll
    for (int i = 0; i < 2; ++i)
#pragma unroll
      for (int j = 0; j < 4; ++j)
        acc[i][j] = __builtin_amdgcn_mfma_f32_16x16x32_f16(af[i], bfr[j], acc[i][j], 0, 0, 0);
    __syncthreads();
  }
  int q4 = ((lane >> 4)) * 4, cl = lane & 15;
#pragma unroll
  for (int i = 0; i < 2; ++i)
#pragma unroll
    for (int rr = 0; rr < 4; ++rr) {
      int row = row0 + mq + i * 16 + q4 + rr;
      int orow = permRows ? inv_perm64(row) : row;
#pragma unroll
      for (int j = 0; j < 4; ++j)
        C[(size_t)orow * ldc + n0 + nq + j * 16 + cl] = (f16)acc[i][j][rr];
    }
}

// ------- radial[e,c] = (silu(emb@r1+b1)@r2)[e,c], dense, coalesced f16x4 stores -------
#define RHSTR 136   // rhA stride (272 B)
__global__ __launch_bounds__(256) void radial_kernel(
    const float* __restrict__ lens_s,
    const float* __restrict__ r1l, const float* __restrict__ b1l,
    const f16* __restrict__ r2h, f16* __restrict__ rad)
{
  __shared__ float r1s[NBASIS * RHID];
  __shared__ float b1s[RHID];
  __shared__ float lensL[64];
  __shared__ float embs[64][11];
  __shared__ __align__(16) f16 rhA[64 * RHSTR];
  int t = threadIdx.x;
  int lane = t & 63, w = t >> 6;
  int r = lane & 15, q = lane >> 4;
  int e0 = blockIdx.x * 64;

  if (t < 64) lensL[t] = lens_s[e0 + t];
  for (int idx = t; idx < NBASIS * RHID; idx += 256) r1s[idx] = r1l[idx];
  if (t < RHID) b1s[t] = b1l[t];
  __syncthreads();

  // issue B-frag loads early
  int n0w = w * 64;
  f16x8 bfr[4][4];
#pragma unroll
  for (int j = 0; j < 4; ++j)
#pragma unroll
    for (int ks = 0; ks < 4; ++ks)
      bfr[j][ks] = *(const f16x8*)(r2h + (size_t)(n0w + j * 16 + r) * KR2 + ks * 32 + q * 8);

  // cosine basis
  {
    const float step = 5.f / 11.f;
    const float sq = 3.1622776601683795f;   // sqrt(10)
    for (int idx = t; idx < 640; idx += 256) {
      int e = idx & 63, k = idx >> 6;
      float d = (lensL[e] - (float)(k + 1) * step) / step;
      embs[e][k] = (d > -1.f && d < 1.f) ? __cosf(1.5707963267948966f * d) * sq : 0.f;
    }
  }
  __syncthreads();

  // radial MLP -> rhA (k padded to 128)
#pragma unroll
  for (int i = 0; i < 4; ++i) {
    int e = lane;
    int g = i * 4 + w;
    f16x8 v;
#pragma unroll
    for (int kk = 0; kk < 8; ++kk) {
      int k = g * 8 + kk;
      float s = 0.f;
      if (k < RHID) {
        s = b1s[k];
#pragma unroll
        for (int jj = 0; jj < NBASIS; ++jj) s += embs[e][jj] * r1s[jj * RHID + k];
        s = __fdividef(s, 1.f + __expf(-s));
      }
      v[kk] = (f16)s;
    }
    *(f16x8*)&rhA[e * RHSTR + g * 8] = v;
  }
  __syncthreads();

  // MFMA: radial[64,256] = rh[64,128] @ r2h_perm^T ; wave w -> true cols w*64..
  f32x4 acc[4][4];
#pragma unroll
  for (int i = 0; i < 4; ++i)
#pragma unroll
    for (int j = 0; j < 4; ++j) acc[i][j] = (f32x4){0.f, 0.f, 0.f, 0.f};
#pragma unroll
  for (int ks = 0; ks < 4; ++ks) {
    f16x8 af[4];
#pragma unroll
    for (int i = 0; i < 4; ++i)
      af[i] = *(const f16x8*)&rhA[(i * 16 + r) * RHSTR + ks * 32 + q * 8];
#pragma unroll
    for (int i = 0; i < 4; ++i)
#pragma unroll
      for (int j = 0; j < 4; ++j)
        acc[i][j] = __builtin_amdgcn_mfma_f32_16x16x32_f16(af[i], bfr[j][ks], acc[i][j], 0, 0, 0);
  }

  // stores: MFMA n-index j*16+r computed true col r*4+j -> pack j as f16x4, coalesced
#pragma unroll
  for (int i = 0; i < 4; ++i)
#pragma unroll
    for (int rr = 0; rr < 4; ++rr) {
      int m = i * 16 + q * 4 + rr;
      f16x4 o;
#pragma unroll
      for (int j = 0; j < 4; ++j) o[j] = (f16)acc[i][j][rr];
      *(f16x4*)(rad + (size_t)(e0 + m) * HD + n0w + r * 4) = o;
    }
}

// ------- gather: T[n,a,c] = sum_{e->n} sh[e,a] * rad[e,c] * h[src_e,c] -------
// 2-edge unroll (2x loads in flight), 5000 blocks (2 node-phases each)
__global__ __launch_bounds__(256) void gather2_kernel(
    const int* __restrict__ rowptr, const f16* __restrict__ rad,
    const f16* __restrict__ h, const f16* __restrict__ sh_s,
    f16* __restrict__ T)
{
  int t = threadIdx.x;
  int half = t >> 7, lc = t & 127;
  int base = blockIdx.x * 4;
  for (int s = 0; s < 2; ++s) {
    int n = base + s * 2 + half;
    int beg = rowptr[n], end = rowptr[n + 1];
    float a0[NSH], a1[NSH];
#pragma unroll
    for (int a = 0; a < NSH; ++a) { a0[a] = 0.f; a1[a] = 0.f; }
    int j = beg;
    for (; j + 2 <= end; j += 2) {
      const f16* she0 = sh_s + (size_t)j * SHSTR;
      const f16* she1 = she0 + SHSTR;
      f16x8 s80 = *(const f16x8*)she0;
      f16x8 s81 = *(const f16x8*)she1;
      float s8v0 = (float)she0[8];
      float s8v1 = (float)she1[8];
      int src0 = *(const int*)(she0 + 10);
      int src1 = *(const int*)(she1 + 10);
      f16x2 rv0 = *(const f16x2*)(rad + (size_t)j * HD + 2 * lc);
      f16x2 rv1 = *(const f16x2*)(rad + (size_t)(j + 1) * HD + 2 * lc);
      f16x2 hv0 = *(const f16x2*)(h + (size_t)src0 * HD + 2 * lc);
      f16x2 hv1 = *(const f16x2*)(h + (size_t)src1 * HD + 2 * lc);
      float p00 = (float)rv0[0] * (float)hv0[0];
      float p01 = (float)rv0[1] * (float)hv0[1];
      float p10 = (float)rv1[0] * (float)hv1[0];
      float p11 = (float)rv1[1] * (float)hv1[1];
#pragma unroll
      for (int a = 0; a < 8; ++a) {
        float sv0 = (float)s80[a], sv1 = (float)s81[a];
        a0[a] += sv0 * p00 + sv1 * p10;
        a1[a] += sv0 * p01 + sv1 * p11;
      }
      a0[8] += s8v0 * p00 + s8v1 * p10;
      a1[8] += s8v0 * p01 + s8v1 * p11;
    }
    if (j < end) {
      const f16* she = sh_s + (size_t)j * SHSTR;
      f16x8 s8 = *(const f16x8*)she;
      float s8v = (float)she[8];
      int src = *(const int*)(she + 10);
      f16x2 rv = *(const f16x2*)(rad + (size_t)j * HD + 2 * lc);
      f16x2 hv = *(const f16x2*)(h + (size_t)src * HD + 2 * lc);
      float p0 = (float)rv[0] * (float)hv[0];
      float p1 = (float)rv[1] * (float)hv[1];
#pragma unroll
      for (int a = 0; a < 8; ++a) {
        float sv = (float)s8[a];
        a0[a] += sv * p0; a1[a] += sv * p1;
      }
      a0[8] += s8v * p0; a1[8] += s8v * p1;
    }
    f16* Tn = T + (size_t)n * KTP + 2 * lc;
#pragma unroll
    for (int a = 0; a < NSH; ++a) {
      f16x2 o; o[0] = (f16)a0[a]; o[1] = (f16)a1[a];
      *(f16x2*)(Tn + a * HD) = o;
    }
  }
}

// ------- split-K MFMA GEMM: round-11 structure + COALESCED staging lanes -------
// Old A map (row=t&63) made each wave-instr touch 64 cachelines; new map
// (row=t>>2, chunk=t&3) -> 4 consecutive lanes read one 64-B line: 4x fewer
// TA requests. LDS dest layout [chunk][row] unchanged (measured 0 conflicts).
#define GBM 64
#define GBN 128
__global__ __launch_bounds__(256) void gemm_splitk_kernel(
    const f16* __restrict__ A1,   // T [MPAD][2304]
    const f16* __restrict__ A2,   // h [MPAD][256]
    const f16* __restrict__ B,    // Bcat [256][2560] (n-major, perm64 rows)
    float* __restrict__ P)
{
  __shared__ __align__(16) f16 As[4][GBM][8];
  __shared__ __align__(16) f16 Bs[4][GBN][8];
  int t = threadIdx.x;
  int lane = t & 63, w = t >> 6;
  int kc = blockIdx.x;
  int row0 = blockIdx.y * GBM;
  int n0 = blockIdx.z * GBN;
  f32x4 acc[2][4];
#pragma unroll
  for (int i = 0; i < 2; ++i)
#pragma unroll
    for (int j = 0; j < 4; ++j) acc[i][j] = (f32x4){0.f, 0.f, 0.f, 0.f};
  int mq = (w & 1) * 32, nq = (w >> 1) * 64;
  int kbeg = kc * KCH;
  int arow = t >> 2, acc4 = t & 3;     // A: 4 lanes per row -> 64-B segments

  for (int k0 = kbeg; k0 < kbeg + KCH; k0 += 32) {
    {
      const f16* ga = (k0 < KTP)
          ? (A1 + (size_t)(row0 + arow) * KTP + k0 + acc4 * 8)
          : (A2 + (size_t)(row0 + arow) * HD + (k0 - KTP) + acc4 * 8);
      *(uint4*)&As[acc4][arow][0] = *(const uint4*)ga;
    }
#pragma unroll
    for (int u = 0; u < 2; ++u) {
      int idx = t + u * 256;
      int nn = idx >> 2, ch = idx & 3;  // B: 4 lanes per row
      *(uint4*)&Bs[ch][nn][0] = *(const uint4*)(B + (size_t)(n0 + nn) * KTOT + k0 + ch * 8);
    }
    __syncthreads();
    int q = lane >> 4, r = lane & 15;
    f16x8 af[2], bfr[4];
#pragma unroll
    for (int i = 0; i < 2; ++i) af[i] = *(const f16x8*)&As[q][mq + i * 16 + r][0];
#pragma unroll
    for (int j = 0; j < 4; ++j) bfr[j] = *(const f16x8*)&Bs[q][nq + j * 16 + r][0];
#pragma unroll
    for (int i = 0; i < 2; ++i)
#pragma unroll
      for (int j = 0; j < 4; ++j)
        acc[i][j] = __builtin_amdgcn_mfma_f32_16x16x32_f16(af[i], bfr[j], acc[i][j], 0, 0, 0);
    __syncthreads();
  }
  // thread-canonical slab layout: region [8192] floats, slab s=(i*4+j) holds
  // 256 threads x f32x4 contiguous -> fully coalesced
  float* Pb = P + ((size_t)(blockIdx.z * NRT + blockIdx.y) * SPLITK + kc) * 8192;
#pragma unroll
  for (int i = 0; i < 2; ++i)
#pragma unroll
    for (int j = 0; j < 4; ++j)
      *(f32x4*)(Pb + (i * 4 + j) * 1024 + t * 4) = acc[i][j];
}

// ------- reduce: C = gelu(sum_kc P), permuted-B f16x4 epilogue -------
__global__ __launch_bounds__(256) void reduce_kernel(const float* __restrict__ P,
                                                     f16* __restrict__ C)
{
  int t = threadIdx.x;
  int row0 = blockIdx.x * GBM;
  int n0 = blockIdx.y * GBN;
  const float* Pb = P + ((size_t)(blockIdx.y * NRT + blockIdx.x) * SPLITK) * 8192;
  f32x4 s[8];
#pragma unroll
  for (int sl = 0; sl < 8; ++sl) {
    f32x4 v = *(const f32x4*)(Pb + sl * 1024 + t * 4);
#pragma unroll
    for (int kc = 1; kc < SPLITK; ++kc)
      v += *(const f32x4*)(Pb + kc * 8192 + sl * 1024 + t * 4);
    s[sl] = v;
  }
  int lane = t & 63, w = t >> 6;
  int mq = (w & 1) * 32, nq = (w >> 1) * 64;
  int q4 = (lane >> 4) * 4, cl = lane & 15;
#pragma unroll
  for (int i = 0; i < 2; ++i)
#pragma unroll
    for (int rr = 0; rr < 4; ++rr) {
      int row = row0 + mq + i * 16 + q4 + rr;   // MPAD-padded: no guard
      f16x4 o;
#pragma unroll
      for (int j = 0; j < 4; ++j) o[j] = (f16)gelu_tanh(s[i * 4 + j][rr]);
      *(f16x4*)(C + (size_t)row * HD + n0 + nq + cl * 4) = o;
    }
}

// ---------------- node_out + graph sums ----------------
__global__ void node_out_kernel(const f16* __restrict__ h,
                                const float* __restrict__ Wout,
                                const int* __restrict__ batch,
                                float* __restrict__ sums,
                                float* __restrict__ cnts)
{
  int n = blockIdx.x * 4 + (threadIdx.x >> 6);
  int lane = threadIdx.x & 63;
  if (n >= NNODE) return;
  float s = 0.f;
#pragma unroll
  for (int t = 0; t < 4; ++t) {
    int c = lane + t * 64;
    s += (float)h[(size_t)n * HD + c] * Wout[c];
  }
#pragma unroll
  for (int off = 32; off > 0; off >>= 1) s += __shfl_down(s, off);
  if (lane == 0) {
    int g = batch[n];
    atomicAdd(&sums[g], s);
    atomicAdd(&cnts[g], 1.f);
  }
}

__global__ void finalize_kernel(const float* __restrict__ sums,
                                const float* __restrict__ cnts,
                                float* __restrict__ out)
{
  int g = threadIdx.x;
  if (g < NGRAPH) out[g] = sums[g] / fmaxf(cnts[g], 1.f);
}

// ---------------- host launch ----------------
extern "C" void kernel_launch(void* const* d_in, const int* in_sizes, int n_in,
                              void* d_out, int out_size, void* d_ws, size_t ws_size,
                              hipStream_t stream)
{
  (void)in_sizes; (void)n_in; (void)out_size;
  const float* x     = (const float*)d_in[0];
  const float* pos   = (const float*)d_in[1];
  const float* shift = (const float*)d_in[2];
  const float* lat   = (const float*)d_in[3];
  const float* Wemb  = (const float*)d_in[4];
  const float* r1    = (const float*)d_in[5];
  const float* b1    = (const float*)d_in[6];
  const float* r2    = (const float*)d_in[7];
  const float* Wtp   = (const float*)d_in[8];
  const float* Wself = (const float*)d_in[9];
  const float* Wskip = (const float*)d_in[10];
  const float* Wout  = (const float*)d_in[11];
  const int*   eidx  = (const int*)d_in[12];
  const int*   batch = (const int*)d_in[13];
  float* out = (float*)d_out;

  char* ws = (char*)d_ws;
  size_t off = 0;
  auto alloc = [&](size_t bytes) -> char* {
    char* p = ws + off;
    off += (bytes + 255) & ~(size_t)255;
    return p;
  };
  f16*   sh_s    = (f16*)alloc((size_t)NEDGE * SHSTR * 2);      //   7.68 MB
  float* lens_s  = (float*)alloc((size_t)NEDGE * 4);            //   0.96 MB
  f16*   hA      = (f16*)alloc((size_t)MPAD * HD * 2);          //  10.29 MB
  f16*   hB      = (f16*)alloc((size_t)MPAD * HD * 2);          //  10.29 MB
  f16*   T       = (f16*)alloc((size_t)MPAD * KTP * 2);         //  92.60 MB
  f16*   rad     = (f16*)alloc((size_t)NEDGE * HD * 2);         // 122.88 MB
  f16*   Bcat    = (f16*)alloc((size_t)HD * KTOT * 2);          //   1.31 MB
  f16*   r2h     = (f16*)alloc((size_t)HD * KR2 * 2);           //   64 KB
  f16*   Wtp16   = (f16*)alloc((size_t)KTP * HD * 2);           //   1.18 MB
  f16*   WselfT16= (f16*)alloc((size_t)HD * HD * 2);            //   0.13 MB
  int*   rowptr  = (int*)alloc((size_t)(NNODE + 1) * 4);
  int*   deg     = (int*)alloc((size_t)NNODE * 4);
  int*   cursor  = (int*)alloc((size_t)NNODE * 4);
  float* sums    = (float*)alloc((size_t)NGRAPH * 4);
  float* cnts    = (float*)alloc((size_t)NGRAPH * 4);
  if (off > ws_size) return;  // ~247.7 MB

  // unions into rad (dead at those phases):
  f16*   xh      = rad;                              // embed phase
  f16*   WembT16 = rad + (size_t)MPAD * KEMB;
  float* P       = (float*)rad;                      // split-K partials (82.3 MB), after gather2

  hipMemsetAsync(deg, 0, (size_t)NNODE * 4, stream);
  hipMemsetAsync(cursor, 0, (size_t)NNODE * 4, stream);
  hipMemsetAsync(sums, 0, (size_t)NGRAPH * 4, stream);
  hipMemsetAsync(cnts, 0, (size_t)NGRAPH * 4, stream);

  const int EB = (NEDGE + 255) / 256;
  deg_hist_kernel<<<EB, 256, 0, stream>>>(eidx, deg);
  scan_kernel<<<1, 256, 0, stream>>>(deg, rowptr);
  edge_geom_kernel<<<EB, 256, 0, stream>>>(pos, shift, lat, eidx, batch,
                                           rowptr, cursor, sh_s, lens_s);

  // h0 = x @ W_embed via MFMA (no row permutation)
  convert_x_kernel<<<MPAD / 2, 256, 0, stream>>>(x, xh);
  convert_wemb_kernel<<<HD, KEMB, 0, stream>>>(Wemb, WembT16);
  {
    dim3 eg(MPAD / 64, HD / 128);
    gemm_nt_kernel<<<eg, 256, 0, stream>>>(xh, WembT16, hA, KEMB, HD, 0);
  }

  f16* hcur = hA;
  f16* hnxt = hB;
  dim3 ggrid(SPLITK, NRT, 2);              // 2512 blocks, 9.8/CU
  dim3 rgrid(NRT, 2);                      // 628 blocks
  dim3 wgrid(HD / 64, KTP / 128);          // (4, 18)
  for (int l = 0; l < NLAYER; ++l) {
    const float* r1l = r1 + (size_t)l * NBASIS * RHID;
    const float* b1l = b1 + (size_t)l * RHID;
    const float* r2l = r2 + (size_t)l * RHID * HD;
    const float* Wtp_l = Wtp + (size_t)l * NSH * HD * HD;
    const float* Wself_l = Wself + (size_t)l * HD * HD;
    const float* Wskip_l = Wskip + (size_t)l * HD * HD;

    prep_kernel<<<KTP + 512 + 256, 256, 0, stream>>>(Wtp_l, Wself_l, Wskip_l, r2l,
                                                     Wtp16, WselfT16, Bcat, r2h);
    gemm_nt_kernel<<<wgrid, 256, 0, stream>>>(WselfT16, Wtp16, Bcat, HD, KTOT, 1);

    radial_kernel<<<NEDGE / 64, 256, 0, stream>>>(lens_s, r1l, b1l, r2h, rad);
    gather2_kernel<<<NNODE / 4, 256, 0, stream>>>(rowptr, rad, hcur, sh_s, T);
    gemm_splitk_kernel<<<ggrid, 256, 0, stream>>>(T, hcur, Bcat, P);
    reduce_kernel<<<rgrid, 256, 0, stream>>>(P, hnxt);
    f16* tmp = hcur; hcur = hnxt; hnxt = tmp;
  }

  node_out_kernel<<<NNODE / 4, 256, 0, stream>>>(hcur, Wout, batch, sums, cnts);
  finalize_kernel<<<1, 256, 0, stream>>>(sums, cnts, out);
}

// Round 15
// 811.115 us; speedup vs baseline: 1.4279x; 1.0485x over previous
//
#include <hip/hip_runtime.h>
#include <hip/hip_bf16.h>
#include <cstddef>
#include <cstdint>

#define NNODE  20000
#define MPAD   20096        // 314*64
#define NEDGE  240000
#define NGRAPH 200
#define DIN    118
#define HD     256
#define NBASIS 10
#define RHID   100
#define NLAYER 3
#define NSH    9
#define SHSTR  16           // sh row stride in f16 (32 B); [8]=Y8, [10..11]=src bits
#define KTP    (NSH * HD)   // 2304
#define KTOT   (KTP + HD)   // 2560
#define KR2    128          // padded radial K
#define KEMB   128          // padded embed K (118 -> 128)
#define SPLITK 4
#define KCH    (KTOT / SPLITK)   // 640
#define NRT    (MPAD / 64)       // 314 row tiles

typedef _Float16 f16;
typedef _Float16 f16x2 __attribute__((ext_vector_type(2)));
typedef _Float16 f16x4 __attribute__((ext_vector_type(4)));
typedef _Float16 f16x8 __attribute__((ext_vector_type(8)));
typedef float    f32x4 __attribute__((ext_vector_type(4)));

__device__ __forceinline__ float gelu_tanh(float v) {
  float v3 = v * v * v;
  return 0.5f * v * (1.f + tanhf(0.7978845608028654f * (v + 0.044715f * v3)));
}

// within 64-group: physical row rho holds true column perm(rho)
__device__ __forceinline__ int perm64(int rho) {
  return (rho & ~63) | ((rho & 15) * 4 + ((rho >> 4) & 3));
}
__device__ __forceinline__ int inv_perm64(int n) {
  return (n & ~63) | (((n & 3) << 4) | ((n >> 2) & 15));
}

// ---------------- CSR build ----------------
__global__ void deg_hist_kernel(const int* __restrict__ ei, int* __restrict__ deg)
{
  int e = blockIdx.x * 256 + threadIdx.x;
  if (e >= NEDGE) return;
  atomicAdd(&deg[ei[NEDGE + e]], 1);
}

__global__ void scan_kernel(const int* __restrict__ deg, int* __restrict__ rowptr)
{
  __shared__ int part[256];
  int t = threadIdx.x;
  const int chunk = (NNODE + 255) / 256;
  int start = t * chunk;
  int end = min(start + chunk, NNODE);
  int s = 0;
  for (int i = start; i < end; ++i) s += deg[i];
  part[t] = s;
  __syncthreads();
  for (int off = 1; off < 256; off <<= 1) {
    int v = (t >= off) ? part[t - off] : 0;
    __syncthreads();
    part[t] += v;
    __syncthreads();
  }
  int run = (t == 0) ? 0 : part[t - 1];
  for (int i = start; i < end; ++i) { rowptr[i] = run; run += deg[i]; }
  if (t == 255) rowptr[NNODE] = run;
}

// -------- edge geometry + scatter into CSR (dst-sorted) position --------
__global__ void edge_geom_kernel(const float* __restrict__ pos,
                                 const float* __restrict__ shift,
                                 const float* __restrict__ lat,
                                 const int* __restrict__ ei,
                                 const int* __restrict__ batch,
                                 const int* __restrict__ rowptr,
                                 int* __restrict__ cursor,
                                 f16* __restrict__ sh_s,
                                 float* __restrict__ lens_s)
{
  int e = blockIdx.x * 256 + threadIdx.x;
  if (e >= NEDGE) return;
  int src = ei[e];
  int dst = ei[NEDGE + e];
  int b = batch[src];
  const float* L = lat + (size_t)b * 9;
  float s0 = shift[e * 3 + 0], s1 = shift[e * 3 + 1], s2 = shift[e * 3 + 2];
  float ev[3];
#pragma unroll
  for (int j = 0; j < 3; ++j)
    ev[j] = pos[dst * 3 + j] - pos[src * 3 + j] + s0 * L[j] + s1 * L[3 + j] + s2 * L[6 + j];
  float len = sqrtf(ev[0] * ev[0] + ev[1] * ev[1] + ev[2] * ev[2]);
  float inv = 1.f / (len + 1e-12f);
  float x = ev[0] * inv, y = ev[1] * inv, z = ev[2] * inv;
  const float c1 = 1.7320508075688772f;   // sqrt(3)
  const float c2 = 3.872983346207417f;    // sqrt(15)
  int p = atomicAdd(&cursor[dst], 1);
  int si = rowptr[dst] + p;
  f16* she = sh_s + (size_t)si * SHSTR;
  she[0] = (f16)1.f;
  she[1] = (f16)(c1 * x);
  she[2] = (f16)(c1 * y);
  she[3] = (f16)(c1 * z);
  she[4] = (f16)(c2 * x * y);
  she[5] = (f16)(c2 * y * z);
  she[6] = (f16)(1.1180339887498949f * (3.f * z * z - 1.f));  // sqrt(5)/2
  she[7] = (f16)(c2 * x * z);
  she[8] = (f16)(1.9364916731037085f * (x * x - y * y));      // sqrt(15)/2
  she[9] = (f16)0.f;
  *(int*)(she + 10) = src;            // src bits in slots 10-11 (4B-aligned)
  she[12] = (f16)0.f; she[13] = (f16)0.f; she[14] = (f16)0.f; she[15] = (f16)0.f;
  lens_s[si] = len;
}

// ---------------- merged per-layer weight prep ----------------
__global__ void prep_kernel(const float* __restrict__ Wtp_l,
                            const float* __restrict__ Wself_l,
                            const float* __restrict__ Wskip_l,
                            const float* __restrict__ r2l,
                            f16* __restrict__ Wtp16,
                            f16* __restrict__ WselfT16,
                            f16* __restrict__ Bcat,
                            f16* __restrict__ r2h)
{
  int b = blockIdx.x, t = threadIdx.x;
  if (b < KTP) {
    int i = b * 256 + t;
    Wtp16[i] = (f16)Wtp_l[i];
  } else if (b < KTP + 256) {
    int n = b - KTP;
    WselfT16[(size_t)n * HD + t] = (f16)(Wself_l[(size_t)t * HD + n] * 0.28867513459481287f);
  } else if (b < KTP + 512) {
    int rho = b - KTP - 256;            // physical (permuted) Bcat row
    int pcol = perm64(rho);             // true column it holds
    Bcat[(size_t)rho * KTOT + KTP + t] = (f16)Wskip_l[(size_t)t * HD + pcol];
  } else {
    int rho = b - KTP - 512;
    if (t < KR2) {
      int p = perm64(rho);
      r2h[(size_t)rho * KR2 + t] = (t < RHID) ? (f16)r2l[(size_t)t * HD + p] : (f16)0.f;
    }
  }
}

// -------- embed conversions --------
__global__ void convert_x_kernel(const float* __restrict__ x, f16* __restrict__ xh)
{
  int i = blockIdx.x * 2 + (threadIdx.x >> 7);
  int k = threadIdx.x & 127;
  xh[(size_t)i * KEMB + k] = (i < NNODE && k < DIN) ? (f16)x[(size_t)i * DIN + k] : (f16)0.f;
}

__global__ void convert_wemb_kernel(const float* __restrict__ Wemb, f16* __restrict__ WembT16)
{
  int n = blockIdx.x, k = threadIdx.x;
  WembT16[(size_t)n * KEMB + k] = (k < DIN) ? (f16)Wemb[(size_t)k * HD + n] : (f16)0.f;
}

// small MFMA GEMM: C[M][ldc] = A[M][K] @ B^T, B n-major [N][K].
// permRows: store output row r at physical row inv_perm64(r) (for permuted Bcat).
__global__ __launch_bounds__(256) void gemm_nt_kernel(
    const f16* __restrict__ A, const f16* __restrict__ B,
    f16* __restrict__ C, int K, int ldc, int permRows)
{
  __shared__ __align__(16) f16 As[4][64][8];
  __shared__ __align__(16) f16 Bs[4][128][8];
  int t = threadIdx.x;
  int lane = t & 63, w = t >> 6;
  int row0 = blockIdx.x * 64;
  int n0 = blockIdx.y * 128;
  f32x4 acc[2][4];
#pragma unroll
  for (int i = 0; i < 2; ++i)
#pragma unroll
    for (int j = 0; j < 4; ++j) acc[i][j] = (f32x4){0.f, 0.f, 0.f, 0.f};
  int mq = (w & 1) * 32, nq = (w >> 1) * 64;
  for (int k0 = 0; k0 < K; k0 += 32) {
    {
      int row = t & 63, cc = t >> 6;
      *(uint4*)&As[cc][row][0] = *(const uint4*)(A + (size_t)(row0 + row) * K + k0 + cc * 8);
    }
#pragma unroll
    for (int u = 0; u < 2; ++u) {
      int idx = t + u * 256;
      int ch = idx >> 7, nn = idx & 127;
      *(uint4*)&Bs[ch][nn][0] = *(const uint4*)(B + (size_t)(n0 + nn) * K + k0 + ch * 8);
    }
    __syncthreads();
    int q = lane >> 4, r = lane & 15;
    f16x8 af[2], bfr[4];
#pragma unroll
    for (int i = 0; i < 2; ++i) af[i] = *(const f16x8*)&As[q][mq + i * 16 + r][0];
#pragma unroll
    for (int j = 0; j < 4; ++j) bfr[j] = *(const f16x8*)&Bs[q][nq + j * 16 + r][0];
#pragma unroll
    for (int i = 0; i < 2; ++i)
#pragma unroll
      for (int j = 0; j < 4; ++j)
        acc[i][j] = __builtin_amdgcn_mfma_f32_16x16x32_f16(af[i], bfr[j], acc[i][j], 0, 0, 0);
    __syncthreads();
  }
  int q4 = ((lane >> 4)) * 4, cl = lane & 15;
#pragma unroll
  for (int i = 0; i < 2; ++i)
#pragma unroll
    for (int rr = 0; rr < 4; ++rr) {
      int row = row0 + mq + i * 16 + q4 + rr;
      int orow = permRows ? inv_perm64(row) : row;
#pragma unroll
      for (int j = 0; j < 4; ++j)
        C[(size_t)orow * ldc + n0 + nq + j * 16 + cl] = (f16)acc[i][j][rr];
    }
}

// ------- radial[e,c] = (silu(emb@r1+b1)@r2)[e,c] -------
// v2: per-thread register basis (no cos/emb LDS phases, 2 barriers total),
// fdot2 MLP (f16x2 pairs, f32 accumulate), k trimmed to chunks g<13 (k<104).
#define RHSTR 136   // rhA stride (272 B)
__global__ __launch_bounds__(256) void radial_kernel(
    const float* __restrict__ lens_s,
    const float* __restrict__ r1l, const float* __restrict__ b1l,
    const f16* __restrict__ r2h, f16* __restrict__ rad)
{
  __shared__ f16x2 r1p[RHID][6];   // basis pairs; j=10 -> bias, j=11 -> 0
  __shared__ __align__(16) f16 rhA[64 * RHSTR];
  int t = threadIdx.x;
  int lane = t & 63, w = t >> 6;
  int r = lane & 15, q = lane >> 4;
  int e0 = blockIdx.x * 64;

  // stage r1 pairs (bias folded in as basis #10)
  for (int idx = t; idx < RHID * 6; idx += 256) {
    int k = idx / 6, p = idx % 6;
    int j0 = 2 * p, j1 = 2 * p + 1;
    float v0 = (j0 < NBASIS) ? r1l[j0 * RHID + k] : (j0 == NBASIS ? b1l[k] : 0.f);
    float v1 = (j1 < NBASIS) ? r1l[j1 * RHID + k] : (j1 == NBASIS ? b1l[k] : 0.f);
    f16x2 pr; pr[0] = (f16)v0; pr[1] = (f16)v1;
    r1p[k][p] = pr;
  }

  // B-frag loads early (r2h, L2-resident)
  int n0w = w * 64;
  f16x8 bfr[4][4];
#pragma unroll
  for (int j = 0; j < 4; ++j)
#pragma unroll
    for (int ks = 0; ks < 4; ++ks)
      bfr[j][ks] = *(const f16x8*)(r2h + (size_t)(n0w + j * 16 + r) * KR2 + ks * 32 + q * 8);

  // per-thread cosine basis for edge e=lane (waves duplicate — trivial)
  float len = lens_s[e0 + lane];
  f16x2 embp[6];
  {
    const float step = 5.f / 11.f;
    const float sq = 3.1622776601683795f;   // sqrt(10)
    f16 etmp[12];
#pragma unroll
    for (int k = 0; k < NBASIS; ++k) {
      float d = (len - (float)(k + 1) * step) / step;
      etmp[k] = (d > -1.f && d < 1.f) ? (f16)(__cosf(1.5707963267948966f * d) * sq) : (f16)0.f;
    }
    etmp[10] = (f16)1.f;    // bias slot
    etmp[11] = (f16)0.f;
#pragma unroll
    for (int p = 0; p < 6; ++p) { embp[p][0] = etmp[2 * p]; embp[p][1] = etmp[2 * p + 1]; }
  }
  __syncthreads();   // r1p ready

  // MLP -> rhA (k < 104 computed; rest zero)
#pragma unroll
  for (int i = 0; i < 4; ++i) {
    int g = i * 4 + w;
    f16x8 v;
#pragma unroll
    for (int kk = 0; kk < 8; ++kk) v[kk] = (f16)0.f;
    if (g < 13) {
#pragma unroll
      for (int kk = 0; kk < 8; ++kk) {
        int k = g * 8 + kk;
        if (k < RHID) {
          float s = 0.f;
#pragma unroll
          for (int p = 0; p < 6; ++p)
            s = __builtin_amdgcn_fdot2(embp[p], r1p[k][p], s, false);
          s = __fdividef(s, 1.f + __expf(-s));
          v[kk] = (f16)s;
        }
      }
    }
    *(f16x8*)&rhA[lane * RHSTR + g * 8] = v;
  }
  __syncthreads();

  // MFMA: radial[64,256] = rh[64,128] @ r2h_perm^T ; wave w -> true cols w*64..
  f32x4 acc[4][4];
#pragma unroll
  for (int i = 0; i < 4; ++i)
#pragma unroll
    for (int j = 0; j < 4; ++j) acc[i][j] = (f32x4){0.f, 0.f, 0.f, 0.f};
#pragma unroll
  for (int ks = 0; ks < 4; ++ks) {
    f16x8 af[4];
#pragma unroll
    for (int i = 0; i < 4; ++i)
      af[i] = *(const f16x8*)&rhA[(i * 16 + r) * RHSTR + ks * 32 + q * 8];
#pragma unroll
    for (int i = 0; i < 4; ++i)
#pragma unroll
      for (int j = 0; j < 4; ++j)
        acc[i][j] = __builtin_amdgcn_mfma_f32_16x16x32_f16(af[i], bfr[j][ks], acc[i][j], 0, 0, 0);
  }

  // stores: MFMA n-index j*16+r computed true col r*4+j -> pack j as f16x4, coalesced
#pragma unroll
  for (int i = 0; i < 4; ++i)
#pragma unroll
    for (int rr = 0; rr < 4; ++rr) {
      int m = i * 16 + q * 4 + rr;
      f16x4 o;
#pragma unroll
      for (int j = 0; j < 4; ++j) o[j] = (f16)acc[i][j][rr];
      *(f16x4*)(rad + (size_t)(e0 + m) * HD + n0w + r * 4) = o;
    }
}

// ------- gather: T[n,a,c] = sum_{e->n} sh[e,a] * rad[e,c] * h[src_e,c] -------
// 2-edge unroll (2x loads in flight), 5000 blocks (2 node-phases each)
__global__ __launch_bounds__(256) void gather2_kernel(
    const int* __restrict__ rowptr, const f16* __restrict__ rad,
    const f16* __restrict__ h, const f16* __restrict__ sh_s,
    f16* __restrict__ T)
{
  int t = threadIdx.x;
  int half = t >> 7, lc = t & 127;
  int base = blockIdx.x * 4;
  for (int s = 0; s < 2; ++s) {
    int n = base + s * 2 + half;
    int beg = rowptr[n], end = rowptr[n + 1];
    float a0[NSH], a1[NSH];
#pragma unroll
    for (int a = 0; a < NSH; ++a) { a0[a] = 0.f; a1[a] = 0.f; }
    int j = beg;
    for (; j + 2 <= end; j += 2) {
      const f16* she0 = sh_s + (size_t)j * SHSTR;
      const f16* she1 = she0 + SHSTR;
      f16x8 s80 = *(const f16x8*)she0;
      f16x8 s81 = *(const f16x8*)she1;
      float s8v0 = (float)she0[8];
      float s8v1 = (float)she1[8];
      int src0 = *(const int*)(she0 + 10);
      int src1 = *(const int*)(she1 + 10);
      f16x2 rv0 = *(const f16x2*)(rad + (size_t)j * HD + 2 * lc);
      f16x2 rv1 = *(const f16x2*)(rad + (size_t)(j + 1) * HD + 2 * lc);
      f16x2 hv0 = *(const f16x2*)(h + (size_t)src0 * HD + 2 * lc);
      f16x2 hv1 = *(const f16x2*)(h + (size_t)src1 * HD + 2 * lc);
      float p00 = (float)rv0[0] * (float)hv0[0];
      float p01 = (float)rv0[1] * (float)hv0[1];
      float p10 = (float)rv1[0] * (float)hv1[0];
      float p11 = (float)rv1[1] * (float)hv1[1];
#pragma unroll
      for (int a = 0; a < 8; ++a) {
        float sv0 = (float)s80[a], sv1 = (float)s81[a];
        a0[a] += sv0 * p00 + sv1 * p10;
        a1[a] += sv0 * p01 + sv1 * p11;
      }
      a0[8] += s8v0 * p00 + s8v1 * p10;
      a1[8] += s8v0 * p01 + s8v1 * p11;
    }
    if (j < end) {
      const f16* she = sh_s + (size_t)j * SHSTR;
      f16x8 s8 = *(const f16x8*)she;
      float s8v = (float)she[8];
      int src = *(const int*)(she + 10);
      f16x2 rv = *(const f16x2*)(rad + (size_t)j * HD + 2 * lc);
      f16x2 hv = *(const f16x2*)(h + (size_t)src * HD + 2 * lc);
      float p0 = (float)rv[0] * (float)hv[0];
      float p1 = (float)rv[1] * (float)hv[1];
#pragma unroll
      for (int a = 0; a < 8; ++a) {
        float sv = (float)s8[a];
        a0[a] += sv * p0; a1[a] += sv * p1;
      }
      a0[8] += s8v * p0; a1[8] += s8v * p1;
    }
    f16* Tn = T + (size_t)n * KTP + 2 * lc;
#pragma unroll
    for (int a = 0; a < NSH; ++a) {
      f16x2 o; o[0] = (f16)a0[a]; o[1] = (f16)a1[a];
      *(f16x2*)(Tn + a * HD) = o;
    }
  }
}

// ------- split-K MFMA GEMM: LDS staged + coalesced staging lanes (round-14) -------
#define GBM 64
#define GBN 128
__global__ __launch_bounds__(256) void gemm_splitk_kernel(
    const f16* __restrict__ A1,   // T [MPAD][2304]
    const f16* __restrict__ A2,   // h [MPAD][256]
    const f16* __restrict__ B,    // Bcat [256][2560] (n-major, perm64 rows)
    float* __restrict__ P)
{
  __shared__ __align__(16) f16 As[4][GBM][8];
  __shared__ __align__(16) f16 Bs[4][GBN][8];
  int t = threadIdx.x;
  int lane = t & 63, w = t >> 6;
  int kc = blockIdx.x;
  int row0 = blockIdx.y * GBM;
  int n0 = blockIdx.z * GBN;
  f32x4 acc[2][4];
#pragma unroll
  for (int i = 0; i < 2; ++i)
#pragma unroll
    for (int j = 0; j < 4; ++j) acc[i][j] = (f32x4){0.f, 0.f, 0.f, 0.f};
  int mq = (w & 1) * 32, nq = (w >> 1) * 64;
  int kbeg = kc * KCH;
  int arow = t >> 2, acc4 = t & 3;     // A: 4 lanes per row -> 64-B segments

  for (int k0 = kbeg; k0 < kbeg + KCH; k0 += 32) {
    {
      const f16* ga = (k0 < KTP)
          ? (A1 + (size_t)(row0 + arow) * KTP + k0 + acc4 * 8)
          : (A2 + (size_t)(row0 + arow) * HD + (k0 - KTP) + acc4 * 8);
      *(uint4*)&As[acc4][arow][0] = *(const uint4*)ga;
    }
#pragma unroll
    for (int u = 0; u < 2; ++u) {
      int idx = t + u * 256;
      int nn = idx >> 2, ch = idx & 3;  // B: 4 lanes per row
      *(uint4*)&Bs[ch][nn][0] = *(const uint4*)(B + (size_t)(n0 + nn) * KTOT + k0 + ch * 8);
    }
    __syncthreads();
    int q = lane >> 4, r = lane & 15;
    f16x8 af[2], bfr[4];
#pragma unroll
    for (int i = 0; i < 2; ++i) af[i] = *(const f16x8*)&As[q][mq + i * 16 + r][0];
#pragma unroll
    for (int j = 0; j < 4; ++j) bfr[j] = *(const f16x8*)&Bs[q][nq + j * 16 + r][0];
#pragma unroll
    for (int i = 0; i < 2; ++i)
#pragma unroll
      for (int j = 0; j < 4; ++j)
        acc[i][j] = __builtin_amdgcn_mfma_f32_16x16x32_f16(af[i], bfr[j], acc[i][j], 0, 0, 0);
    __syncthreads();
  }
  float* Pb = P + ((size_t)(blockIdx.z * NRT + blockIdx.y) * SPLITK + kc) * 8192;
#pragma unroll
  for (int i = 0; i < 2; ++i)
#pragma unroll
    for (int j = 0; j < 4; ++j)
      *(f32x4*)(Pb + (i * 4 + j) * 1024 + t * 4) = acc[i][j];
}

// ------- reduce: C = gelu(sum_kc P), permuted-B f16x4 epilogue -------
__global__ __launch_bounds__(256) void reduce_kernel(const float* __restrict__ P,
                                                     f16* __restrict__ C)
{
  int t = threadIdx.x;
  int row0 = blockIdx.x * GBM;
  int n0 = blockIdx.y * GBN;
  const float* Pb = P + ((size_t)(blockIdx.y * NRT + blockIdx.x) * SPLITK) * 8192;
  f32x4 s[8];
#pragma unroll
  for (int sl = 0; sl < 8; ++sl) {
    f32x4 v = *(const f32x4*)(Pb + sl * 1024 + t * 4);
#pragma unroll
    for (int kc = 1; kc < SPLITK; ++kc)
      v += *(const f32x4*)(Pb + kc * 8192 + sl * 1024 + t * 4);
    s[sl] = v;
  }
  int lane = t & 63, w = t >> 6;
  int mq = (w & 1) * 32, nq = (w >> 1) * 64;
  int q4 = (lane >> 4) * 4, cl = lane & 15;
#pragma unroll
  for (int i = 0; i < 2; ++i)
#pragma unroll
    for (int rr = 0; rr < 4; ++rr) {
      int row = row0 + mq + i * 16 + q4 + rr;   // MPAD-padded: no guard
      f16x4 o;
#pragma unroll
      for (int j = 0; j < 4; ++j) o[j] = (f16)gelu_tanh(s[i * 4 + j][rr]);
      *(f16x4*)(C + (size_t)row * HD + n0 + nq + cl * 4) = o;
    }
}

// ---------------- node_out + graph sums ----------------
__global__ void node_out_kernel(const f16* __restrict__ h,
                                const float* __restrict__ Wout,
                                const int* __restrict__ batch,
                                float* __restrict__ sums,
                                float* __restrict__ cnts)
{
  int n = blockIdx.x * 4 + (threadIdx.x >> 6);
  int lane = threadIdx.x & 63;
  if (n >= NNODE) return;
  float s = 0.f;
#pragma unroll
  for (int t = 0; t < 4; ++t) {
    int c = lane + t * 64;
    s += (float)h[(size_t)n * HD + c] * Wout[c];
  }
#pragma unroll
  for (int off = 32; off > 0; off >>= 1) s += __shfl_down(s, off);
  if (lane == 0) {
    int g = batch[n];
    atomicAdd(&sums[g], s);
    atomicAdd(&cnts[g], 1.f);
  }
}

__global__ void finalize_kernel(const float* __restrict__ sums,
                                const float* __restrict__ cnts,
                                float* __restrict__ out)
{
  int g = threadIdx.x;
  if (g < NGRAPH) out[g] = sums[g] / fmaxf(cnts[g], 1.f);
}

// ---------------- host launch ----------------
extern "C" void kernel_launch(void* const* d_in, const int* in_sizes, int n_in,
                              void* d_out, int out_size, void* d_ws, size_t ws_size,
                              hipStream_t stream)
{
  (void)in_sizes; (void)n_in; (void)out_size;
  const float* x     = (const float*)d_in[0];
  const float* pos   = (const float*)d_in[1];
  const float* shift = (const float*)d_in[2];
  const float* lat   = (const float*)d_in[3];
  const float* Wemb  = (const float*)d_in[4];
  const float* r1    = (const float*)d_in[5];
  const float* b1    = (const float*)d_in[6];
  const float* r2    = (const float*)d_in[7];
  const float* Wtp   = (const float*)d_in[8];
  const float* Wself = (const float*)d_in[9];
  const float* Wskip = (const float*)d_in[10];
  const float* Wout  = (const float*)d_in[11];
  const int*   eidx  = (const int*)d_in[12];
  const int*   batch = (const int*)d_in[13];
  float* out = (float*)d_out;

  char* ws = (char*)d_ws;
  size_t off = 0;
  auto alloc = [&](size_t bytes) -> char* {
    char* p = ws + off;
    off += (bytes + 255) & ~(size_t)255;
    return p;
  };
  f16*   sh_s    = (f16*)alloc((size_t)NEDGE * SHSTR * 2);      //   7.68 MB
  float* lens_s  = (float*)alloc((size_t)NEDGE * 4);            //   0.96 MB
  f16*   hA      = (f16*)alloc((size_t)MPAD * HD * 2);          //  10.29 MB
  f16*   hB      = (f16*)alloc((size_t)MPAD * HD * 2);          //  10.29 MB
  f16*   T       = (f16*)alloc((size_t)MPAD * KTP * 2);         //  92.60 MB
  f16*   rad     = (f16*)alloc((size_t)NEDGE * HD * 2);         // 122.88 MB
  f16*   Bcat    = (f16*)alloc((size_t)HD * KTOT * 2);          //   1.31 MB
  f16*   r2h     = (f16*)alloc((size_t)HD * KR2 * 2);           //   64 KB
  f16*   Wtp16   = (f16*)alloc((size_t)KTP * HD * 2);           //   1.18 MB
  f16*   WselfT16= (f16*)alloc((size_t)HD * HD * 2);            //   0.13 MB
  int*   rowptr  = (int*)alloc((size_t)(NNODE + 1) * 4);
  int*   deg     = (int*)alloc((size_t)NNODE * 4);
  int*   cursor  = (int*)alloc((size_t)NNODE * 4);
  float* sums    = (float*)alloc((size_t)NGRAPH * 4);
  float* cnts    = (float*)alloc((size_t)NGRAPH * 4);
  if (off > ws_size) return;  // ~247.7 MB

  // unions into rad (dead at those phases):
  f16*   xh      = rad;                              // embed phase
  f16*   WembT16 = rad + (size_t)MPAD * KEMB;
  float* P       = (float*)rad;                      // split-K partials (82.3 MB), after gather2

  hipMemsetAsync(deg, 0, (size_t)NNODE * 4, stream);
  hipMemsetAsync(cursor, 0, (size_t)NNODE * 4, stream);
  hipMemsetAsync(sums, 0, (size_t)NGRAPH * 4, stream);
  hipMemsetAsync(cnts, 0, (size_t)NGRAPH * 4, stream);

  const int EB = (NEDGE + 255) / 256;
  deg_hist_kernel<<<EB, 256, 0, stream>>>(eidx, deg);
  scan_kernel<<<1, 256, 0, stream>>>(deg, rowptr);
  edge_geom_kernel<<<EB, 256, 0, stream>>>(pos, shift, lat, eidx, batch,
                                           rowptr, cursor, sh_s, lens_s);

  // h0 = x @ W_embed via MFMA (no row permutation)
  convert_x_kernel<<<MPAD / 2, 256, 0, stream>>>(x, xh);
  convert_wemb_kernel<<<HD, KEMB, 0, stream>>>(Wemb, WembT16);
  {
    dim3 eg(MPAD / 64, HD / 128);
    gemm_nt_kernel<<<eg, 256, 0, stream>>>(xh, WembT16, hA, KEMB, HD, 0);
  }

  f16* hcur = hA;
  f16* hnxt = hB;
  dim3 ggrid(SPLITK, NRT, 2);              // 2512 blocks, 9.8/CU
  dim3 rgrid(NRT, 2);                      // 628 blocks
  dim3 wgrid(HD / 64, KTP / 128);          // (4, 18)
  for (int l = 0; l < NLAYER; ++l) {
    const float* r1l = r1 + (size_t)l * NBASIS * RHID;
    const float* b1l = b1 + (size_t)l * RHID;
    const float* r2l = r2 + (size_t)l * RHID * HD;
    const float* Wtp_l = Wtp + (size_t)l * NSH * HD * HD;
    const float* Wself_l = Wself + (size_t)l * HD * HD;
    const float* Wskip_l = Wskip + (size_t)l * HD * HD;

    prep_kernel<<<KTP + 512 + 256, 256, 0, stream>>>(Wtp_l, Wself_l, Wskip_l, r2l,
                                                     Wtp16, WselfT16, Bcat, r2h);
    gemm_nt_kernel<<<wgrid, 256, 0, stream>>>(WselfT16, Wtp16, Bcat, HD, KTOT, 1);

    radial_kernel<<<NEDGE / 64, 256, 0, stream>>>(lens_s, r1l, b1l, r2h, rad);
    gather2_kernel<<<NNODE / 4, 256, 0, stream>>>(rowptr, rad, hcur, sh_s, T);
    gemm_splitk_kernel<<<ggrid, 256, 0, stream>>>(T, hcur, Bcat, P);
    reduce_kernel<<<rgrid, 256, 0, stream>>>(P, hnxt);
    f16* tmp = hcur; hcur = hnxt; hnxt = tmp;
  }

  node_out_kernel<<<NNODE / 4, 256, 0, stream>>>(hcur, Wout, batch, sums, cnts);
  finalize_kernel<<<1, 256, 0, stream>>>(sums, cnts, out);
}